// Round 9
// baseline (1480.161 us; speedup 1.0000x reference)
//
#include <hip/hip_runtime.h>
#include <cmath>

#define E_ 64
#define H_ 4
#define B_ 2
#define R_ 1225
#define C_ 512
#define EPS 1e-5f

__device__ __forceinline__ float elu1(float a) { return a > 0.f ? a + 1.f : __expf(a); }

typedef float f32x4 __attribute__((ext_vector_type(4)));
typedef short bf16x8 __attribute__((ext_vector_type(8)));
typedef short bf16x4 __attribute__((ext_vector_type(4)));

__device__ __forceinline__ unsigned short f2bf(float f) {
    union { float f; unsigned u; } c; c.f = f;
    unsigned u = c.u + 0x7FFFu + ((c.u >> 16) & 1u);   // RNE
    return (unsigned short)(u >> 16);
}

__device__ __forceinline__ float bf2f(unsigned short s) {
    union { unsigned u; float f; } c; c.u = ((unsigned)s) << 16;
    return c.f;
}

__device__ __forceinline__ bf16x8 pack8(float4 a, float4 b) {
    bf16x8 r;
    r[0] = (short)f2bf(a.x); r[1] = (short)f2bf(a.y);
    r[2] = (short)f2bf(a.z); r[3] = (short)f2bf(a.w);
    r[4] = (short)f2bf(b.x); r[5] = (short)f2bf(b.y);
    r[6] = (short)f2bf(b.z); r[7] = (short)f2bf(b.w);
    return r;
}

// tanh-approx GELU in sigmoid form (max dev ~3e-4 vs exact-erf)
__device__ __forceinline__ float gelu_fast(float a) {
    const float u = a * (-1.5957691216057308f - 0.0713548162726009f * a * a);
    return a / (1.f + __expf(u));
}

#define SX 264   // LDS row stride (256+8) in bf16

// ---------------------------------------------------------------------------
// Attention math: LN is per-position affine =>
//   q_pre[h] = rstd*dq[h] - rstd*mu*WgQ[h] + CQ[h] + bq[h],  dq = sum wq*g*xv
//   u[h][e]  = g[e]*(M1[h][e] - S1[h]) + lb[e]*sk[h]
//   M1[h][e] = sum_c (k_c*rstd_c) * xv[c,e]   (MFMA on RAW x)
// Round-9: round-7 structure (fused wave-coalesced loads) + (256,4) for
// 4 blocks/CU (VGPR ~60 fits the 128 cap) + deeper load unroll for MLP.
// ---------------------------------------------------------------------------

// ---------------------------------------------------------------------------
// Kernel A: row attention over c (C=512) for each (b, r). 256 thr, 2 tiles.
// ---------------------------------------------------------------------------
__global__ __launch_bounds__(256, 4) void row_attn(
    const float* __restrict__ x,
    const float* __restrict__ wq, const float* __restrict__ bq,
    const float* __restrict__ wk, const float* __restrict__ bk,
    const float* __restrict__ wv, const float* __restrict__ bv,
    const float* __restrict__ wo, const float* __restrict__ bo,
    const float* __restrict__ lng, const float* __restrict__ lnb,
    float* __restrict__ hout)
{
    const int r = blockIdx.x;
    const int b = blockIdx.y;
    const int t = threadIdx.x;
    const int w = t >> 6;
    const int l = t & 63;
    const int lr = l & 15;
    const int lq = l >> 4;

    __shared__ short s_xT[E_][SX];     // raw x, bf16, [e][pos-in-tile]
    __shared__ short s_kb[4][SX];      // k*rstd, bf16
    __shared__ float s_u[H_][E_];
    __shared__ float s_ktv[E_];
    __shared__ float s_wok[E_][H_];
    __shared__ float s_qm[H_];
    __shared__ float s_sk[H_];
    __shared__ float s_S1[H_];
    __shared__ float red_q[4][H_];
    __shared__ float red_k[4][H_];
    __shared__ float red_k2[4][H_];
    __shared__ float s_cst[16];        // WgQ[4] CQ[4] WgK[4] CK[4]

    // block-uniform constants
    if (t < 16) {
        const int h = t & 3;
        const int kind = t >> 2;                    // 0 WgQ, 1 CQ, 2 WgK, 3 CK
        const float* wm = (kind < 2) ? wq : wk;
        const float* vm = (kind & 1) ? lnb : lng;
        float acc = 0.f;
        for (int e = 0; e < E_; ++e) acc += wm[h * E_ + e] * vm[e];
        s_cst[t] = acc;
    }
    __syncthreads();

    const size_t RC = (size_t)R_ * C_;
    const float* xbase = x + (size_t)b * E_ * RC + (size_t)r * C_;

    float aq[H_]  = {0.f, 0.f, 0.f, 0.f};
    float ak[H_]  = {0.f, 0.f, 0.f, 0.f};
    float ak2[H_] = {0.f, 0.f, 0.f, 0.f};
    float qs[2][H_];
    f32x4 uacc; uacc[0] = uacc[1] = uacc[2] = uacc[3] = 0.f;

    #pragma unroll 1
    for (int it = 0; it < 2; ++it) {
        const float* xp = xbase + it * 256 + t;
        float s = 0.f, ss = 0.f;
        float dq[H_] = {0.f, 0.f, 0.f, 0.f};
        float dk[H_] = {0.f, 0.f, 0.f, 0.f};
        // unroll 32: deeper in-flight load pipeline (fits the 128-reg cap)
        #pragma unroll 32
        for (int e = 0; e < E_; ++e) {
            const float xv = xp[(size_t)e * RC];
            s += xv; ss += xv * xv;
            const float t1 = lng[e] * xv;
            #pragma unroll
            for (int h = 0; h < H_; ++h) { dq[h] += wq[h * E_ + e] * t1; dk[h] += wk[h * E_ + e] * t1; }
            s_xT[e][t] = (short)f2bf(xv);
        }
        const float mu = s * (1.f / E_);
        const float rstd = rsqrtf(ss * (1.f / E_) - mu * mu + EPS);
        const float mr = mu * rstd;
        #pragma unroll
        for (int h = 0; h < H_; ++h) {
            const float qv = elu1(rstd * dq[h] - mr * s_cst[h]     + s_cst[4 + h]  + bq[h]);
            const float kv = elu1(rstd * dk[h] - mr * s_cst[8 + h] + s_cst[12 + h] + bk[h]);
            qs[it][h] = qv;
            aq[h] += qv; ak[h] += kv; ak2[h] += kv * mr;
            s_kb[h][t] = (short)f2bf(kv * rstd);
        }
        __syncthreads();
        #pragma unroll
        for (int ks = 0; ks < 8; ++ks) {
            bf16x8 af;
            #pragma unroll
            for (int i = 0; i < 8; ++i) af[i] = 0;
            if (lr < 4) af = *reinterpret_cast<const bf16x8*>(&s_kb[lr][ks * 32 + lq * 8]);
            const bf16x8 bf = *reinterpret_cast<const bf16x8*>(&s_xT[w * 16 + lr][ks * 32 + lq * 8]);
            uacc = __builtin_amdgcn_mfma_f32_16x16x32_bf16(af, bf, uacc, 0, 0, 0);
        }
        __syncthreads();
    }

    // reductions of sum_q, sum_k, sum k*rstd*mu
    #pragma unroll
    for (int h = 0; h < H_; ++h) {
        #pragma unroll
        for (int off = 32; off; off >>= 1) {
            aq[h] += __shfl_xor(aq[h], off, 64);
            ak[h] += __shfl_xor(ak[h], off, 64);
            ak2[h] += __shfl_xor(ak2[h], off, 64);
        }
    }
    if (l == 0) {
        #pragma unroll
        for (int h = 0; h < H_; ++h) { red_q[w][h] = aq[h]; red_k[w][h] = ak[h]; red_k2[w][h] = ak2[h]; }
    }
    __syncthreads();
    if (t < H_) {
        float sq = 0.f, sk = 0.f, s1 = 0.f;
        #pragma unroll
        for (int w2 = 0; w2 < 4; ++w2) { sq += red_q[w2][t]; sk += red_k[w2][t]; s1 += red_k2[w2][t]; }
        s_qm[t] = sq * (1.f / C_);
        s_sk[t] = sk;
        s_S1[t] = s1;
    }
    __syncthreads();
    // u[h][e] = g[e]*(M1 - S1[h]) + lb[e]*sk[h]
    if (lq == 0) {
        const int e = w * 16 + lr;
        #pragma unroll
        for (int i = 0; i < 4; ++i)
            s_u[i][e] = lng[e] * (uacc[i] - s_S1[i]) + lnb[e] * s_sk[i];
    }
    __syncthreads();
    if (t < E_) {
        const int h = t >> 4;
        float acc = 0.f;
        #pragma unroll
        for (int e = 0; e < E_; ++e) acc += wv[t * E_ + e] * s_u[h][e];
        s_ktv[t] = acc / s_sk[h] + bv[t];
    }
    __syncthreads();
    if (t < E_) {
        #pragma unroll
        for (int h = 0; h < H_; ++h) {
            float acc = 0.f;
            #pragma unroll
            for (int d = 0; d < 16; ++d) acc += wo[t * E_ + h * 16 + d] * s_ktv[h * 16 + d];
            s_wok[t][h] = acc;
        }
    }
    __syncthreads();

    #pragma unroll 1
    for (int it = 0; it < 2; ++it) {
        const int c = it * 256 + t;
        const float* xp = xbase + c;
        float qn[H_];
        #pragma unroll
        for (int h = 0; h < H_; ++h) qn[h] = qs[it][h] / s_qm[h];
        float* hp = hout + ((size_t)(b * C_ + c) * R_ + r) * E_;
        #pragma unroll 4
        for (int e4 = 0; e4 < 16; ++e4) {
            float4 o;
            float* ov = (float*)&o;
            #pragma unroll
            for (int i = 0; i < 4; ++i) {
                const int e = e4 * 4 + i;
                float tt = bo[e];
                #pragma unroll
                for (int h = 0; h < H_; ++h) tt += qn[h] * s_wok[e][h];
                ov[i] = xp[(size_t)e * RC] + tt;
            }
            *reinterpret_cast<float4*>(hp + e4 * 4) = o;
        }
    }
}

// ---------------------------------------------------------------------------
// Kernel B: col attention over r (R=1225) for each (b, c). In-place, 5 tiles.
// ---------------------------------------------------------------------------
__global__ __launch_bounds__(256, 4) void col_attn(
    float* __restrict__ hbuf,
    const float* __restrict__ wq, const float* __restrict__ bq,
    const float* __restrict__ wk, const float* __restrict__ bk,
    const float* __restrict__ wv, const float* __restrict__ bv,
    const float* __restrict__ wo, const float* __restrict__ bo,
    const float* __restrict__ lng, const float* __restrict__ lnb)
{
    const int c = blockIdx.x;
    const int b = blockIdx.y;
    const int t = threadIdx.x;
    const int w = t >> 6;
    const int l = t & 63;
    const int lr = l & 15;
    const int lq = l >> 4;

    __shared__ short s_xT[E_][SX];
    __shared__ short s_kb[4][SX];
    __shared__ float s_u[H_][E_];
    __shared__ float s_ktv[E_];
    __shared__ float s_wok[E_][H_];
    __shared__ float s_qm[H_];
    __shared__ float s_sk[H_];
    __shared__ float s_S1[H_];
    __shared__ float red_q[4][H_];
    __shared__ float red_k[4][H_];
    __shared__ float red_k2[4][H_];
    __shared__ float s_cst[16];

    if (t < 16) {
        const int h = t & 3;
        const int kind = t >> 2;
        const float* wm = (kind < 2) ? wq : wk;
        const float* vm = (kind & 1) ? lnb : lng;
        float acc = 0.f;
        for (int e = 0; e < E_; ++e) acc += wm[h * E_ + e] * vm[e];
        s_cst[t] = acc;
    }
    __syncthreads();

    float* hp0 = hbuf + (size_t)(b * C_ + c) * R_ * E_;

    float aq[H_]  = {0.f, 0.f, 0.f, 0.f};
    float ak[H_]  = {0.f, 0.f, 0.f, 0.f};
    float ak2[H_] = {0.f, 0.f, 0.f, 0.f};
    unsigned qs_pk[5][2];
    f32x4 uacc; uacc[0] = uacc[1] = uacc[2] = uacc[3] = 0.f;

    #pragma unroll 1
    for (int it = 0; it < 5; ++it) {
        const int rr = it * 256 + t;
        if (rr < R_) {
            const float4* pp4 = (const float4*)(hp0 + (size_t)rr * E_);
            float s = 0.f, ss = 0.f;
            float dq[H_] = {0.f, 0.f, 0.f, 0.f};
            float dk[H_] = {0.f, 0.f, 0.f, 0.f};
            // unroll 8: deeper in-flight float4 pipeline (32 regs)
            #pragma unroll 8
            for (int e4 = 0; e4 < 16; ++e4) {
                const float4 v4 = pp4[e4];
                const float* vv = (const float*)&v4;
                #pragma unroll
                for (int i = 0; i < 4; ++i) {
                    const int e = e4 * 4 + i;
                    const float xv = vv[i];
                    s += xv; ss += xv * xv;
                    const float t1 = lng[e] * xv;
                    #pragma unroll
                    for (int h = 0; h < H_; ++h) { dq[h] += wq[h * E_ + e] * t1; dk[h] += wk[h * E_ + e] * t1; }
                    s_xT[e][t] = (short)f2bf(xv);
                }
            }
            const float mu = s * (1.f / E_);
            const float rstd = rsqrtf(ss * (1.f / E_) - mu * mu + EPS);
            const float mr = mu * rstd;
            float qv[H_];
            #pragma unroll
            for (int h = 0; h < H_; ++h) {
                qv[h] = elu1(rstd * dq[h] - mr * s_cst[h]     + s_cst[4 + h]  + bq[h]);
                const float kv = elu1(rstd * dk[h] - mr * s_cst[8 + h] + s_cst[12 + h] + bk[h]);
                aq[h] += qv[h]; ak[h] += kv; ak2[h] += kv * mr;
                s_kb[h][t] = (short)f2bf(kv * rstd);
            }
            qs_pk[it][0] = ((unsigned)f2bf(qv[1]) << 16) | f2bf(qv[0]);
            qs_pk[it][1] = ((unsigned)f2bf(qv[3]) << 16) | f2bf(qv[2]);
        } else {
            #pragma unroll
            for (int e = 0; e < E_; ++e) s_xT[e][t] = 0;
            #pragma unroll
            for (int h = 0; h < H_; ++h) s_kb[h][t] = 0;
            qs_pk[it][0] = 0; qs_pk[it][1] = 0;
        }
        __syncthreads();
        #pragma unroll
        for (int ks = 0; ks < 8; ++ks) {
            bf16x8 af;
            #pragma unroll
            for (int i = 0; i < 8; ++i) af[i] = 0;
            if (lr < 4) af = *reinterpret_cast<const bf16x8*>(&s_kb[lr][ks * 32 + lq * 8]);
            const bf16x8 bf = *reinterpret_cast<const bf16x8*>(&s_xT[w * 16 + lr][ks * 32 + lq * 8]);
            uacc = __builtin_amdgcn_mfma_f32_16x16x32_bf16(af, bf, uacc, 0, 0, 0);
        }
        __syncthreads();
    }

    #pragma unroll
    for (int h = 0; h < H_; ++h) {
        #pragma unroll
        for (int off = 32; off; off >>= 1) {
            aq[h] += __shfl_xor(aq[h], off, 64);
            ak[h] += __shfl_xor(ak[h], off, 64);
            ak2[h] += __shfl_xor(ak2[h], off, 64);
        }
    }
    if (l == 0) {
        #pragma unroll
        for (int h = 0; h < H_; ++h) { red_q[w][h] = aq[h]; red_k[w][h] = ak[h]; red_k2[w][h] = ak2[h]; }
    }
    __syncthreads();
    if (t < H_) {
        float sq = 0.f, sk = 0.f, s1 = 0.f;
        #pragma unroll
        for (int w2 = 0; w2 < 4; ++w2) { sq += red_q[w2][t]; sk += red_k[w2][t]; s1 += red_k2[w2][t]; }
        s_qm[t] = sq * (1.f / R_);
        s_sk[t] = sk;
        s_S1[t] = s1;
    }
    __syncthreads();
    if (lq == 0) {
        const int e = w * 16 + lr;
        #pragma unroll
        for (int i = 0; i < 4; ++i)
            s_u[i][e] = lng[e] * (uacc[i] - s_S1[i]) + lnb[e] * s_sk[i];
    }
    __syncthreads();
    if (t < E_) {
        const int h = t >> 4;
        float acc = 0.f;
        #pragma unroll
        for (int e = 0; e < E_; ++e) acc += wv[t * E_ + e] * s_u[h][e];
        s_ktv[t] = acc / s_sk[h] + bv[t];
    }
    __syncthreads();
    if (t < E_) {
        #pragma unroll
        for (int h = 0; h < H_; ++h) {
            float acc = 0.f;
            #pragma unroll
            for (int d = 0; d < 16; ++d) acc += wo[t * E_ + h * 16 + d] * s_ktv[h * 16 + d];
            s_wok[t][h] = acc;
        }
    }
    __syncthreads();

    #pragma unroll 1
    for (int it = 0; it < 5; ++it) {
        const int rr = it * 256 + t;
        if (rr >= R_) continue;
        float qn[H_];
        qn[0] = bf2f((unsigned short)(qs_pk[it][0] & 0xFFFF)) / s_qm[0];
        qn[1] = bf2f((unsigned short)(qs_pk[it][0] >> 16))    / s_qm[1];
        qn[2] = bf2f((unsigned short)(qs_pk[it][1] & 0xFFFF)) / s_qm[2];
        qn[3] = bf2f((unsigned short)(qs_pk[it][1] >> 16))    / s_qm[3];
        float* pp = hp0 + (size_t)rr * E_;
        #pragma unroll 4
        for (int e4 = 0; e4 < 16; ++e4) {
            const float4 v4 = *reinterpret_cast<const float4*>(pp + e4 * 4);
            const float* hv4 = (const float*)&v4;
            float4 o;
            float* ov = (float*)&o;
            #pragma unroll
            for (int i = 0; i < 4; ++i) {
                const int e = e4 * 4 + i;
                float tt = bo[e];
                #pragma unroll
                for (int h = 0; h < H_; ++h) tt += qn[h] * s_wok[e][h];
                ov[i] = hv4[i] + tt;
            }
            *reinterpret_cast<float4*>(pp + e4 * 4) = o;
        }
    }
}

// ---------------------------------------------------------------------------
// prep_weights: fp32 -> bf16 for w1/w2.
// ---------------------------------------------------------------------------
__global__ __launch_bounds__(256) void prep_weights(
    const float* __restrict__ w1, const float* __restrict__ w2,
    short* __restrict__ w1b, short* __restrict__ w2b)
{
    const int i = blockIdx.x * 256 + threadIdx.x;
    if (i < 16384) w1b[i] = (short)f2bf(w1[i]);
    else           w2b[i - 16384] = (short)f2bf(w2[i - 16384]);
}

// ---------------------------------------------------------------------------
// Kernel C: MFMA bf16 FFN (unchanged).
// ---------------------------------------------------------------------------
#define SA 72
#define SG 264
#define SO 65

template <bool PREP>
__global__ __launch_bounds__(256) void ffn_mfma(
    const float* __restrict__ hbuf,
    const float* __restrict__ lng, const float* __restrict__ lnb,
    const float* __restrict__ w1, const short* __restrict__ w1b,
    const float* __restrict__ b1,
    const float* __restrict__ w2, const short* __restrict__ w2b,
    const float* __restrict__ b2,
    float* __restrict__ out)
{
    __shared__ __align__(16) char smem[33792 + 16640];
    short* s_g = (short*)smem;
    short* s_a = (short*)(smem + 33792);
    float* s_o = (float*)(smem + 33792);

    const int t = threadIdx.x;
    const int w = t >> 6;
    const int l = t & 63;
    const int lr = l & 15;
    const int lq = l >> 4;

    const int bid = blockIdx.x;
    const int cb  = bid & 7;
    const int rem = bid >> 3;
    const int r   = rem % R_;
    const int b   = rem / R_;
    const int c0  = cb * 64;

    {
        const int m  = t >> 2;
        const int qi = t & 3;
        const float* hp = hbuf + ((size_t)(b * C_ + c0 + m) * R_ + r) * E_ + qi * 16;
        const float4* hp4 = (const float4*)hp;
        float4 v0 = hp4[0], v1 = hp4[1], v2 = hp4[2], v3 = hp4[3];
        float hv[16];
        hv[0]=v0.x; hv[1]=v0.y; hv[2]=v0.z; hv[3]=v0.w;
        hv[4]=v1.x; hv[5]=v1.y; hv[6]=v1.z; hv[7]=v1.w;
        hv[8]=v2.x; hv[9]=v2.y; hv[10]=v2.z; hv[11]=v2.w;
        hv[12]=v3.x; hv[13]=v3.y; hv[14]=v3.z; hv[15]=v3.w;
        float s = 0.f, ss = 0.f;
        #pragma unroll
        for (int i = 0; i < 16; ++i) { s += hv[i]; ss += hv[i] * hv[i]; }
        s  += __shfl_xor(s, 1, 64);  s  += __shfl_xor(s, 2, 64);
        ss += __shfl_xor(ss, 1, 64); ss += __shfl_xor(ss, 2, 64);
        const float mu = s * (1.f / 64.f);
        const float rstd = rsqrtf(ss * (1.f / 64.f) - mu * mu + EPS);
        bf16x8 o0, o1;
        #pragma unroll
        for (int i = 0; i < 8; ++i) {
            const int e = qi * 16 + i;
            o0[i] = (short)f2bf((hv[i] - mu) * rstd * lng[e] + lnb[e]);
        }
        #pragma unroll
        for (int i = 0; i < 8; ++i) {
            const int e = qi * 16 + 8 + i;
            o1[i] = (short)f2bf((hv[8 + i] - mu) * rstd * lng[e] + lnb[e]);
        }
        *reinterpret_cast<bf16x8*>(&s_a[m * SA + qi * 16])     = o0;
        *reinterpret_cast<bf16x8*>(&s_a[m * SA + qi * 16 + 8]) = o1;
    }
    __syncthreads();

    {
        bf16x8 bfr[4][2];
        #pragma unroll
        for (int mt = 0; mt < 4; ++mt)
            #pragma unroll
            for (int ks = 0; ks < 2; ++ks)
                bfr[mt][ks] = *reinterpret_cast<const bf16x8*>(
                    &s_a[(mt * 16 + lr) * SA + ks * 32 + lq * 8]);

        #pragma unroll
        for (int nn = 0; nn < 4; ++nn) {
            const int jt = w * 4 + nn;
            bf16x8 afr[2];
            if (PREP) {
                #pragma unroll
                for (int ks = 0; ks < 2; ++ks)
                    afr[ks] = *reinterpret_cast<const bf16x8*>(
                        w1b + (size_t)(jt * 16 + lr) * 64 + ks * 32 + lq * 8);
            } else {
                #pragma unroll
                for (int ks = 0; ks < 2; ++ks) {
                    const float4* wp = (const float4*)(w1 + (size_t)(jt * 16 + lr) * 64 + ks * 32 + lq * 8);
                    afr[ks] = pack8(wp[0], wp[1]);
                }
            }
            f32x4 acc[4];
            #pragma unroll
            for (int mt = 0; mt < 4; ++mt) { acc[mt][0]=0.f; acc[mt][1]=0.f; acc[mt][2]=0.f; acc[mt][3]=0.f; }
            #pragma unroll
            for (int ks = 0; ks < 2; ++ks)
                #pragma unroll
                for (int mt = 0; mt < 4; ++mt)
                    acc[mt] = __builtin_amdgcn_mfma_f32_16x16x32_bf16(afr[ks], bfr[mt][ks], acc[mt], 0, 0, 0);

            const float4 b1v = *reinterpret_cast<const float4*>(&b1[jt * 16 + lq * 4]);
            const float* b1p = (const float*)&b1v;
            #pragma unroll
            for (int mt = 0; mt < 4; ++mt) {
                const int m = mt * 16 + lr;
                bf16x4 pk;
                #pragma unroll
                for (int i = 0; i < 4; ++i) {
                    const float aa = acc[mt][i] + b1p[i];
                    pk[i] = (short)f2bf(gelu_fast(aa));
                }
                *reinterpret_cast<bf16x4*>(&s_g[m * SG + jt * 16 + lq * 4]) = pk;
            }
        }
    }
    __syncthreads();

    {
        f32x4 acc2[4];
        #pragma unroll
        for (int mt = 0; mt < 4; ++mt) { acc2[mt][0]=0.f; acc2[mt][1]=0.f; acc2[mt][2]=0.f; acc2[mt][3]=0.f; }
        const int n = w * 16 + lr;
        #pragma unroll
        for (int ks = 0; ks < 8; ++ks) {
            bf16x8 bfr;
            if (PREP) {
                bfr = *reinterpret_cast<const bf16x8*>(w2b + (size_t)n * 256 + ks * 32 + lq * 8);
            } else {
                const float4* wp = (const float4*)(w2 + (size_t)n * 256 + ks * 32 + lq * 8);
                bfr = pack8(wp[0], wp[1]);
            }
            #pragma unroll
            for (int mt = 0; mt < 4; ++mt) {
                const bf16x8 af = *reinterpret_cast<const bf16x8*>(
                    &s_g[(mt * 16 + lr) * SG + ks * 32 + lq * 8]);
                acc2[mt] = __builtin_amdgcn_mfma_f32_16x16x32_bf16(af, bfr, acc2[mt], 0, 0, 0);
            }
        }
        #pragma unroll
        for (int mt = 0; mt < 4; ++mt)
            #pragma unroll
            for (int i = 0; i < 4; ++i)
                s_o[(mt * 16 + lq * 4 + i) * SO + n] = acc2[mt][i];
    }
    __syncthreads();

    {
        const int m  = t & 63;
        const int eb = (t >> 6) * 16;
        const int c  = c0 + m;
        const float* hp = hbuf + ((size_t)(b * C_ + c) * R_ + r) * E_ + eb;
        const float4* hp4 = (const float4*)hp;
        float4 v0 = hp4[0], v1 = hp4[1], v2 = hp4[2], v3 = hp4[3];
        float hv[16];
        hv[0]=v0.x; hv[1]=v0.y; hv[2]=v0.z; hv[3]=v0.w;
        hv[4]=v1.x; hv[5]=v1.y; hv[6]=v1.z; hv[7]=v1.w;
        hv[8]=v2.x; hv[9]=v2.y; hv[10]=v2.z; hv[11]=v2.w;
        hv[12]=v3.x; hv[13]=v3.y; hv[14]=v3.z; hv[15]=v3.w;
        #pragma unroll
        for (int i = 0; i < 16; ++i) {
            const int e = eb + i;
            const float val = s_o[m * SO + e] + b2[e] + hv[i];
            out[(((size_t)b * E_ + e) * R_ + r) * C_ + c] = val;
        }
    }
}

extern "C" void kernel_launch(void* const* d_in, const int* in_sizes, int n_in,
                              void* d_out, int out_size, void* d_ws, size_t ws_size,
                              hipStream_t stream) {
    const float* x      = (const float*)d_in[0];
    const float* row_wq = (const float*)d_in[1];
    const float* row_bq = (const float*)d_in[2];
    const float* row_wk = (const float*)d_in[3];
    const float* row_bk = (const float*)d_in[4];
    const float* row_wv = (const float*)d_in[5];
    const float* row_bv = (const float*)d_in[6];
    const float* row_wo = (const float*)d_in[7];
    const float* row_bo = (const float*)d_in[8];
    const float* col_wq = (const float*)d_in[9];
    const float* col_bq = (const float*)d_in[10];
    const float* col_wk = (const float*)d_in[11];
    const float* col_bk = (const float*)d_in[12];
    const float* col_wv = (const float*)d_in[13];
    const float* col_bv = (const float*)d_in[14];
    const float* col_wo = (const float*)d_in[15];
    const float* col_bo = (const float*)d_in[16];
    const float* rn_g   = (const float*)d_in[17];
    const float* rn_b   = (const float*)d_in[18];
    const float* cn_g   = (const float*)d_in[19];
    const float* cn_b   = (const float*)d_in[20];
    const float* fn_g   = (const float*)d_in[21];
    const float* fn_b   = (const float*)d_in[22];
    const float* w1     = (const float*)d_in[23];
    const float* b1     = (const float*)d_in[24];
    const float* w2     = (const float*)d_in[25];
    const float* b2     = (const float*)d_in[26];

    const size_t need = (size_t)B_ * C_ * R_ * E_ * sizeof(float);
    if (ws_size < need) return;
    float* hbuf = (float*)d_ws;

    const bool prep = (ws_size >= need + 2 * 16384 * sizeof(short) + 256);
    short* w1b = (short*)((char*)d_ws + need);
    short* w2b = w1b + 16384;

    row_attn<<<dim3(R_, B_), 256, 0, stream>>>(
        x, row_wq, row_bq, row_wk, row_bk, row_wv, row_bv, row_wo, row_bo,
        rn_g, rn_b, hbuf);
    col_attn<<<dim3(C_, B_), 256, 0, stream>>>(
        hbuf, col_wq, col_bq, col_wk, col_bk, col_wv, col_bv, col_wo, col_bo,
        cn_g, cn_b);
    if (prep) {
        prep_weights<<<128, 256, 0, stream>>>(w1, w2, w1b, w2b);
        ffn_mfma<true><<<B_ * R_ * 8, 256, 0, stream>>>(
            hbuf, fn_g, fn_b, w1, w1b, b1, w2, w2b, b2, (float*)d_out);
    } else {
        ffn_mfma<false><<<B_ * R_ * 8, 256, 0, stream>>>(
            hbuf, fn_g, fn_b, w1, w1b, b1, w2, w2b, b2, (float*)d_out);
    }
}

// Round 10
// 1315.229 us; speedup vs baseline: 1.1254x; 1.1254x over previous
//
#include <hip/hip_runtime.h>
#include <cmath>

#define E_ 64
#define H_ 4
#define B_ 2
#define R_ 1225
#define C_ 512
#define EPS 1e-5f

__device__ __forceinline__ float elu1(float a) { return a > 0.f ? a + 1.f : __expf(a); }

typedef float f32x4 __attribute__((ext_vector_type(4)));
typedef short bf16x8 __attribute__((ext_vector_type(8)));
typedef short bf16x4 __attribute__((ext_vector_type(4)));

__device__ __forceinline__ unsigned short f2bf(float f) {
    union { float f; unsigned u; } c; c.f = f;
    unsigned u = c.u + 0x7FFFu + ((c.u >> 16) & 1u);   // RNE
    return (unsigned short)(u >> 16);
}

__device__ __forceinline__ float bf2f(unsigned short s) {
    union { unsigned u; float f; } c; c.u = ((unsigned)s) << 16;
    return c.f;
}

__device__ __forceinline__ bf16x8 pack8(float4 a, float4 b) {
    bf16x8 r;
    r[0] = (short)f2bf(a.x); r[1] = (short)f2bf(a.y);
    r[2] = (short)f2bf(a.z); r[3] = (short)f2bf(a.w);
    r[4] = (short)f2bf(b.x); r[5] = (short)f2bf(b.y);
    r[6] = (short)f2bf(b.z); r[7] = (short)f2bf(b.w);
    return r;
}

// tanh-approx GELU in sigmoid form (max dev ~3e-4 vs exact-erf)
__device__ __forceinline__ float gelu_fast(float a) {
    const float u = a * (-1.5957691216057308f - 0.0713548162726009f * a * a);
    return a / (1.f + __expf(u));
}

// ---------------------------------------------------------------------------
// Kernel A v5: row attention, 512 threads, ONE tile (thread t <-> position c=t).
// - single load->MFMA phase (half the barrier rounds of the 256-thr version)
// - MFMA K=512 split across wave pairs (waves 0-3: k-half 0; 4-7: k-half 1)
// - phase E reads x from LDS (bf16) instead of global: no VMEM dependency
//   after the last barrier. LDS ~75KB -> 2 blocks/CU (16 waves/CU).
// Math (verified r6-r8): LN affine fold; u[h][e]=g[e]*(M1-S1[h])+lb[e]*sk[h].
// ---------------------------------------------------------------------------
#define SXR 520   // 512+8 pad

__global__ __launch_bounds__(512, 2) void row_attn(
    const float* __restrict__ x,
    const float* __restrict__ wq, const float* __restrict__ bq,
    const float* __restrict__ wk, const float* __restrict__ bk,
    const float* __restrict__ wv, const float* __restrict__ bv,
    const float* __restrict__ wo, const float* __restrict__ bo,
    const float* __restrict__ lng, const float* __restrict__ lnb,
    float* __restrict__ hout)
{
    const int r = blockIdx.x;
    const int b = blockIdx.y;
    const int t = threadIdx.x;      // 0..511 == c
    const int w = t >> 6;           // wave 0..7
    const int l = t & 63;
    const int lr = l & 15;
    const int lq = l >> 4;

    __shared__ short s_xT[E_][SXR];        // raw x bf16 [e][c]
    __shared__ short s_kb[4][SXR];         // k*rstd bf16
    __shared__ float s_upart[2][H_][E_];   // per-k-half MFMA partials
    __shared__ float s_ktv[E_];
    __shared__ float s_wok[E_][H_];
    __shared__ float s_qm[H_];
    __shared__ float s_sk[H_];
    __shared__ float s_S1[H_];
    __shared__ float red_q[8][H_];
    __shared__ float red_k[8][H_];
    __shared__ float red_k2[8][H_];
    __shared__ float s_cst[16];            // WgQ[4] CQ[4] WgK[4] CK[4]

    if (t < 16) {
        const int h = t & 3;
        const int kind = t >> 2;
        const float* wm = (kind < 2) ? wq : wk;
        const float* vm = (kind & 1) ? lnb : lng;
        float acc = 0.f;
        for (int e = 0; e < E_; ++e) acc += wm[h * E_ + e] * vm[e];
        s_cst[t] = acc;
    }
    __syncthreads();

    const size_t RC = (size_t)R_ * C_;
    const float* xbase = x + (size_t)b * E_ * RC + (size_t)r * C_;

    // ---- phase A+B: load column c=t (wave-coalesced 256B/instr), LN-fold,
    //      q/k, stash bf16 x and k*rstd in LDS ----------------------------
    float qs[H_];
    float aq[H_], ak[H_], ak2[H_];
    {
        const float* xp = xbase + t;
        float s = 0.f, ss = 0.f;
        float dq[H_] = {0.f, 0.f, 0.f, 0.f};
        float dk[H_] = {0.f, 0.f, 0.f, 0.f};
        #pragma unroll 16
        for (int e = 0; e < E_; ++e) {
            const float xv = xp[(size_t)e * RC];
            s += xv; ss += xv * xv;
            const float t1 = lng[e] * xv;
            #pragma unroll
            for (int h = 0; h < H_; ++h) { dq[h] += wq[h * E_ + e] * t1; dk[h] += wk[h * E_ + e] * t1; }
            s_xT[e][t] = (short)f2bf(xv);
        }
        const float mu = s * (1.f / E_);
        const float rstd = rsqrtf(ss * (1.f / E_) - mu * mu + EPS);
        const float mr = mu * rstd;
        #pragma unroll
        for (int h = 0; h < H_; ++h) {
            const float qv = elu1(rstd * dq[h] - mr * s_cst[h]     + s_cst[4 + h]  + bq[h]);
            const float kv = elu1(rstd * dk[h] - mr * s_cst[8 + h] + s_cst[12 + h] + bk[h]);
            qs[h] = qv;
            aq[h] = qv; ak[h] = kv; ak2[h] = kv * mr;
            s_kb[h][t] = (short)f2bf(kv * rstd);
        }
    }
    __syncthreads();

    // ---- MFMA: u = K^T x X, K=512 split across wave pairs ----------------
    {
        const int et = w & 3;      // e-tile
        const int kh = w >> 2;     // k-half
        f32x4 uacc; uacc[0] = uacc[1] = uacc[2] = uacc[3] = 0.f;
        #pragma unroll
        for (int ks = 0; ks < 8; ++ks) {
            const int co = kh * 256 + ks * 32 + lq * 8;
            bf16x8 af;
            #pragma unroll
            for (int i = 0; i < 8; ++i) af[i] = 0;
            if (lr < 4) af = *reinterpret_cast<const bf16x8*>(&s_kb[lr][co]);
            const bf16x8 bf = *reinterpret_cast<const bf16x8*>(&s_xT[et * 16 + lr][co]);
            uacc = __builtin_amdgcn_mfma_f32_16x16x32_bf16(af, bf, uacc, 0, 0, 0);
        }
        if (lq == 0) {
            #pragma unroll
            for (int i = 0; i < 4; ++i) s_upart[kh][i][et * 16 + lr] = uacc[i];
        }
    }

    // ---- wave reductions of sum_q, sum_k, sum k*rstd*mu ------------------
    #pragma unroll
    for (int h = 0; h < H_; ++h) {
        #pragma unroll
        for (int off = 32; off; off >>= 1) {
            aq[h] += __shfl_xor(aq[h], off, 64);
            ak[h] += __shfl_xor(ak[h], off, 64);
            ak2[h] += __shfl_xor(ak2[h], off, 64);
        }
    }
    if (l == 0) {
        #pragma unroll
        for (int h = 0; h < H_; ++h) { red_q[w][h] = aq[h]; red_k[w][h] = ak[h]; red_k2[w][h] = ak2[h]; }
    }
    __syncthreads();
    if (t < H_) {
        float sq = 0.f, sk = 0.f, s1 = 0.f;
        #pragma unroll
        for (int w2 = 0; w2 < 8; ++w2) { sq += red_q[w2][t]; sk += red_k[w2][t]; s1 += red_k2[w2][t]; }
        s_qm[t] = sq * (1.f / C_);
        s_sk[t] = sk;
        s_S1[t] = s1;
    }
    __syncthreads();
    // combine k-halves + LN-fold correction into s_upart[0] (reused as u)
    if (t < H_ * E_) {
        const int h = t >> 6, e = t & 63;
        const float m1 = s_upart[0][h][e] + s_upart[1][h][e];
        s_upart[0][h][e] = lng[e] * (m1 - s_S1[h]) + lnb[e] * s_sk[h];
    }
    __syncthreads();
    if (t < E_) {
        const int h = t >> 4;
        float acc = 0.f;
        #pragma unroll
        for (int e = 0; e < E_; ++e) acc += wv[t * E_ + e] * s_upart[0][h][e];
        s_ktv[t] = acc / s_sk[h] + bv[t];
    }
    __syncthreads();
    if (t < E_) {
        #pragma unroll
        for (int h = 0; h < H_; ++h) {
            float acc = 0.f;
            #pragma unroll
            for (int d = 0; d < 16; ++d) acc += wo[t * E_ + h * 16 + d] * s_ktv[h * 16 + d];
            s_wok[t][h] = acc;
        }
    }
    __syncthreads();

    // ---- phase E: residual from LDS (bf16 x) + h write -------------------
    {
        float qn[H_];
        #pragma unroll
        for (int h = 0; h < H_; ++h) qn[h] = qs[h] / s_qm[h];
        float* hp = hout + ((size_t)(b * C_ + t) * R_ + r) * E_;
        #pragma unroll 4
        for (int e4 = 0; e4 < 16; ++e4) {
            float4 o;
            float* ov = (float*)&o;
            #pragma unroll
            for (int i = 0; i < 4; ++i) {
                const int e = e4 * 4 + i;
                float tt = bo[e];
                #pragma unroll
                for (int h = 0; h < H_; ++h) tt += qn[h] * s_wok[e][h];
                ov[i] = bf2f((unsigned short)s_xT[e][t]) + tt;
            }
            *reinterpret_cast<float4*>(hp + e4 * 4) = o;
        }
    }
}

// ---------------------------------------------------------------------------
// Kernel B: col attention (r8-best settings: bounds (256,3), unroll 4).
// ---------------------------------------------------------------------------
#define SX 264

__global__ __launch_bounds__(256, 3) void col_attn(
    float* __restrict__ hbuf,
    const float* __restrict__ wq, const float* __restrict__ bq,
    const float* __restrict__ wk, const float* __restrict__ bk,
    const float* __restrict__ wv, const float* __restrict__ bv,
    const float* __restrict__ wo, const float* __restrict__ bo,
    const float* __restrict__ lng, const float* __restrict__ lnb)
{
    const int c = blockIdx.x;
    const int b = blockIdx.y;
    const int t = threadIdx.x;
    const int w = t >> 6;
    const int l = t & 63;
    const int lr = l & 15;
    const int lq = l >> 4;

    __shared__ short s_xT[E_][SX];
    __shared__ short s_kb[4][SX];
    __shared__ float s_u[H_][E_];
    __shared__ float s_ktv[E_];
    __shared__ float s_wok[E_][H_];
    __shared__ float s_qm[H_];
    __shared__ float s_sk[H_];
    __shared__ float s_S1[H_];
    __shared__ float red_q[4][H_];
    __shared__ float red_k[4][H_];
    __shared__ float red_k2[4][H_];
    __shared__ float s_cst[16];

    if (t < 16) {
        const int h = t & 3;
        const int kind = t >> 2;
        const float* wm = (kind < 2) ? wq : wk;
        const float* vm = (kind & 1) ? lnb : lng;
        float acc = 0.f;
        for (int e = 0; e < E_; ++e) acc += wm[h * E_ + e] * vm[e];
        s_cst[t] = acc;
    }
    __syncthreads();

    float* hp0 = hbuf + (size_t)(b * C_ + c) * R_ * E_;

    float aq[H_]  = {0.f, 0.f, 0.f, 0.f};
    float ak[H_]  = {0.f, 0.f, 0.f, 0.f};
    float ak2[H_] = {0.f, 0.f, 0.f, 0.f};
    unsigned qs_pk[5][2];
    f32x4 uacc; uacc[0] = uacc[1] = uacc[2] = uacc[3] = 0.f;

    #pragma unroll 1
    for (int it = 0; it < 5; ++it) {
        const int rr = it * 256 + t;
        if (rr < R_) {
            const float4* pp4 = (const float4*)(hp0 + (size_t)rr * E_);
            float s = 0.f, ss = 0.f;
            float dq[H_] = {0.f, 0.f, 0.f, 0.f};
            float dk[H_] = {0.f, 0.f, 0.f, 0.f};
            #pragma unroll 4
            for (int e4 = 0; e4 < 16; ++e4) {
                const float4 v4 = pp4[e4];
                const float* vv = (const float*)&v4;
                #pragma unroll
                for (int i = 0; i < 4; ++i) {
                    const int e = e4 * 4 + i;
                    const float xv = vv[i];
                    s += xv; ss += xv * xv;
                    const float t1 = lng[e] * xv;
                    #pragma unroll
                    for (int h = 0; h < H_; ++h) { dq[h] += wq[h * E_ + e] * t1; dk[h] += wk[h * E_ + e] * t1; }
                    s_xT[e][t] = (short)f2bf(xv);
                }
            }
            const float mu = s * (1.f / E_);
            const float rstd = rsqrtf(ss * (1.f / E_) - mu * mu + EPS);
            const float mr = mu * rstd;
            float qv[H_];
            #pragma unroll
            for (int h = 0; h < H_; ++h) {
                qv[h] = elu1(rstd * dq[h] - mr * s_cst[h]     + s_cst[4 + h]  + bq[h]);
                const float kv = elu1(rstd * dk[h] - mr * s_cst[8 + h] + s_cst[12 + h] + bk[h]);
                aq[h] += qv[h]; ak[h] += kv; ak2[h] += kv * mr;
                s_kb[h][t] = (short)f2bf(kv * rstd);
            }
            qs_pk[it][0] = ((unsigned)f2bf(qv[1]) << 16) | f2bf(qv[0]);
            qs_pk[it][1] = ((unsigned)f2bf(qv[3]) << 16) | f2bf(qv[2]);
        } else {
            #pragma unroll
            for (int e = 0; e < E_; ++e) s_xT[e][t] = 0;
            #pragma unroll
            for (int h = 0; h < H_; ++h) s_kb[h][t] = 0;
            qs_pk[it][0] = 0; qs_pk[it][1] = 0;
        }
        __syncthreads();
        #pragma unroll
        for (int ks = 0; ks < 8; ++ks) {
            bf16x8 af;
            #pragma unroll
            for (int i = 0; i < 8; ++i) af[i] = 0;
            if (lr < 4) af = *reinterpret_cast<const bf16x8*>(&s_kb[lr][ks * 32 + lq * 8]);
            const bf16x8 bf = *reinterpret_cast<const bf16x8*>(&s_xT[w * 16 + lr][ks * 32 + lq * 8]);
            uacc = __builtin_amdgcn_mfma_f32_16x16x32_bf16(af, bf, uacc, 0, 0, 0);
        }
        __syncthreads();
    }

    #pragma unroll
    for (int h = 0; h < H_; ++h) {
        #pragma unroll
        for (int off = 32; off; off >>= 1) {
            aq[h] += __shfl_xor(aq[h], off, 64);
            ak[h] += __shfl_xor(ak[h], off, 64);
            ak2[h] += __shfl_xor(ak2[h], off, 64);
        }
    }
    if (l == 0) {
        #pragma unroll
        for (int h = 0; h < H_; ++h) { red_q[w][h] = aq[h]; red_k[w][h] = ak[h]; red_k2[w][h] = ak2[h]; }
    }
    __syncthreads();
    if (t < H_) {
        float sq = 0.f, sk = 0.f, s1 = 0.f;
        #pragma unroll
        for (int w2 = 0; w2 < 4; ++w2) { sq += red_q[w2][t]; sk += red_k[w2][t]; s1 += red_k2[w2][t]; }
        s_qm[t] = sq * (1.f / R_);
        s_sk[t] = sk;
        s_S1[t] = s1;
    }
    __syncthreads();
    if (lq == 0) {
        const int e = w * 16 + lr;
        #pragma unroll
        for (int i = 0; i < 4; ++i)
            s_u[i][e] = lng[e] * (uacc[i] - s_S1[i]) + lnb[e] * s_sk[i];
    }
    __syncthreads();
    if (t < E_) {
        const int h = t >> 4;
        float acc = 0.f;
        #pragma unroll
        for (int e = 0; e < E_; ++e) acc += wv[t * E_ + e] * s_u[h][e];
        s_ktv[t] = acc / s_sk[h] + bv[t];
    }
    __syncthreads();
    if (t < E_) {
        #pragma unroll
        for (int h = 0; h < H_; ++h) {
            float acc = 0.f;
            #pragma unroll
            for (int d = 0; d < 16; ++d) acc += wo[t * E_ + h * 16 + d] * s_ktv[h * 16 + d];
            s_wok[t][h] = acc;
        }
    }
    __syncthreads();

    #pragma unroll 1
    for (int it = 0; it < 5; ++it) {
        const int rr = it * 256 + t;
        if (rr >= R_) continue;
        float qn[H_];
        qn[0] = bf2f((unsigned short)(qs_pk[it][0] & 0xFFFF)) / s_qm[0];
        qn[1] = bf2f((unsigned short)(qs_pk[it][0] >> 16))    / s_qm[1];
        qn[2] = bf2f((unsigned short)(qs_pk[it][1] & 0xFFFF)) / s_qm[2];
        qn[3] = bf2f((unsigned short)(qs_pk[it][1] >> 16))    / s_qm[3];
        float* pp = hp0 + (size_t)rr * E_;
        #pragma unroll 4
        for (int e4 = 0; e4 < 16; ++e4) {
            const float4 v4 = *reinterpret_cast<const float4*>(pp + e4 * 4);
            const float* hv4 = (const float*)&v4;
            float4 o;
            float* ov = (float*)&o;
            #pragma unroll
            for (int i = 0; i < 4; ++i) {
                const int e = e4 * 4 + i;
                float tt = bo[e];
                #pragma unroll
                for (int h = 0; h < H_; ++h) tt += qn[h] * s_wok[e][h];
                ov[i] = hv4[i] + tt;
            }
            *reinterpret_cast<float4*>(pp + e4 * 4) = o;
        }
    }
}

// ---------------------------------------------------------------------------
// prep_weights: fp32 -> bf16 for w1/w2.
// ---------------------------------------------------------------------------
__global__ __launch_bounds__(256) void prep_weights(
    const float* __restrict__ w1, const float* __restrict__ w2,
    short* __restrict__ w1b, short* __restrict__ w2b)
{
    const int i = blockIdx.x * 256 + threadIdx.x;
    if (i < 16384) w1b[i] = (short)f2bf(w1[i]);
    else           w2b[i - 16384] = (short)f2bf(w2[i - 16384]);
}

// ---------------------------------------------------------------------------
// Kernel C: MFMA bf16 FFN (unchanged).
// ---------------------------------------------------------------------------
#define SA 72
#define SG 264
#define SO 65

template <bool PREP>
__global__ __launch_bounds__(256) void ffn_mfma(
    const float* __restrict__ hbuf,
    const float* __restrict__ lng, const float* __restrict__ lnb,
    const float* __restrict__ w1, const short* __restrict__ w1b,
    const float* __restrict__ b1,
    const float* __restrict__ w2, const short* __restrict__ w2b,
    const float* __restrict__ b2,
    float* __restrict__ out)
{
    __shared__ __align__(16) char smem[33792 + 16640];
    short* s_g = (short*)smem;
    short* s_a = (short*)(smem + 33792);
    float* s_o = (float*)(smem + 33792);

    const int t = threadIdx.x;
    const int w = t >> 6;
    const int l = t & 63;
    const int lr = l & 15;
    const int lq = l >> 4;

    const int bid = blockIdx.x;
    const int cb  = bid & 7;
    const int rem = bid >> 3;
    const int r   = rem % R_;
    const int b   = rem / R_;
    const int c0  = cb * 64;

    {
        const int m  = t >> 2;
        const int qi = t & 3;
        const float* hp = hbuf + ((size_t)(b * C_ + c0 + m) * R_ + r) * E_ + qi * 16;
        const float4* hp4 = (const float4*)hp;
        float4 v0 = hp4[0], v1 = hp4[1], v2 = hp4[2], v3 = hp4[3];
        float hv[16];
        hv[0]=v0.x; hv[1]=v0.y; hv[2]=v0.z; hv[3]=v0.w;
        hv[4]=v1.x; hv[5]=v1.y; hv[6]=v1.z; hv[7]=v1.w;
        hv[8]=v2.x; hv[9]=v2.y; hv[10]=v2.z; hv[11]=v2.w;
        hv[12]=v3.x; hv[13]=v3.y; hv[14]=v3.z; hv[15]=v3.w;
        float s = 0.f, ss = 0.f;
        #pragma unroll
        for (int i = 0; i < 16; ++i) { s += hv[i]; ss += hv[i] * hv[i]; }
        s  += __shfl_xor(s, 1, 64);  s  += __shfl_xor(s, 2, 64);
        ss += __shfl_xor(ss, 1, 64); ss += __shfl_xor(ss, 2, 64);
        const float mu = s * (1.f / 64.f);
        const float rstd = rsqrtf(ss * (1.f / 64.f) - mu * mu + EPS);
        bf16x8 o0, o1;
        #pragma unroll
        for (int i = 0; i < 8; ++i) {
            const int e = qi * 16 + i;
            o0[i] = (short)f2bf((hv[i] - mu) * rstd * lng[e] + lnb[e]);
        }
        #pragma unroll
        for (int i = 0; i < 8; ++i) {
            const int e = qi * 16 + 8 + i;
            o1[i] = (short)f2bf((hv[8 + i] - mu) * rstd * lng[e] + lnb[e]);
        }
        *reinterpret_cast<bf16x8*>(&s_a[m * SA + qi * 16])     = o0;
        *reinterpret_cast<bf16x8*>(&s_a[m * SA + qi * 16 + 8]) = o1;
    }
    __syncthreads();

    {
        bf16x8 bfr[4][2];
        #pragma unroll
        for (int mt = 0; mt < 4; ++mt)
            #pragma unroll
            for (int ks = 0; ks < 2; ++ks)
                bfr[mt][ks] = *reinterpret_cast<const bf16x8*>(
                    &s_a[(mt * 16 + lr) * SA + ks * 32 + lq * 8]);

        #pragma unroll
        for (int nn = 0; nn < 4; ++nn) {
            const int jt = w * 4 + nn;
            bf16x8 afr[2];
            if (PREP) {
                #pragma unroll
                for (int ks = 0; ks < 2; ++ks)
                    afr[ks] = *reinterpret_cast<const bf16x8*>(
                        w1b + (size_t)(jt * 16 + lr) * 64 + ks * 32 + lq * 8);
            } else {
                #pragma unroll
                for (int ks = 0; ks < 2; ++ks) {
                    const float4* wp = (const float4*)(w1 + (size_t)(jt * 16 + lr) * 64 + ks * 32 + lq * 8);
                    afr[ks] = pack8(wp[0], wp[1]);
                }
            }
            f32x4 acc[4];
            #pragma unroll
            for (int mt = 0; mt < 4; ++mt) { acc[mt][0]=0.f; acc[mt][1]=0.f; acc[mt][2]=0.f; acc[mt][3]=0.f; }
            #pragma unroll
            for (int ks = 0; ks < 2; ++ks)
                #pragma unroll
                for (int mt = 0; mt < 4; ++mt)
                    acc[mt] = __builtin_amdgcn_mfma_f32_16x16x32_bf16(afr[ks], bfr[mt][ks], acc[mt], 0, 0, 0);

            const float4 b1v = *reinterpret_cast<const float4*>(&b1[jt * 16 + lq * 4]);
            const float* b1p = (const float*)&b1v;
            #pragma unroll
            for (int mt = 0; mt < 4; ++mt) {
                const int m = mt * 16 + lr;
                bf16x4 pk;
                #pragma unroll
                for (int i = 0; i < 4; ++i) {
                    const float aa = acc[mt][i] + b1p[i];
                    pk[i] = (short)f2bf(gelu_fast(aa));
                }
                *reinterpret_cast<bf16x4*>(&s_g[m * SG + jt * 16 + lq * 4]) = pk;
            }
        }
    }
    __syncthreads();

    {
        f32x4 acc2[4];
        #pragma unroll
        for (int mt = 0; mt < 4; ++mt) { acc2[mt][0]=0.f; acc2[mt][1]=0.f; acc2[mt][2]=0.f; acc2[mt][3]=0.f; }
        const int n = w * 16 + lr;
        #pragma unroll
        for (int ks = 0; ks < 8; ++ks) {
            bf16x8 bfr;
            if (PREP) {
                bfr = *reinterpret_cast<const bf16x8*>(w2b + (size_t)n * 256 + ks * 32 + lq * 8);
            } else {
                const float4* wp = (const float4*)(w2 + (size_t)n * 256 + ks * 32 + lq * 8);
                bfr = pack8(wp[0], wp[1]);
            }
            #pragma unroll
            for (int mt = 0; mt < 4; ++mt) {
                const bf16x8 af = *reinterpret_cast<const bf16x8*>(
                    &s_g[(mt * 16 + lr) * SG + ks * 32 + lq * 8]);
                acc2[mt] = __builtin_amdgcn_mfma_f32_16x16x32_bf16(af, bfr, acc2[mt], 0, 0, 0);
            }
        }
        #pragma unroll
        for (int mt = 0; mt < 4; ++mt)
            #pragma unroll
            for (int i = 0; i < 4; ++i)
                s_o[(mt * 16 + lq * 4 + i) * SO + n] = acc2[mt][i];
    }
    __syncthreads();

    {
        const int m  = t & 63;
        const int eb = (t >> 6) * 16;
        const int c  = c0 + m;
        const float* hp = hbuf + ((size_t)(b * C_ + c) * R_ + r) * E_ + eb;
        const float4* hp4 = (const float4*)hp;
        float4 v0 = hp4[0], v1 = hp4[1], v2 = hp4[2], v3 = hp4[3];
        float hv[16];
        hv[0]=v0.x; hv[1]=v0.y; hv[2]=v0.z; hv[3]=v0.w;
        hv[4]=v1.x; hv[5]=v1.y; hv[6]=v1.z; hv[7]=v1.w;
        hv[8]=v2.x; hv[9]=v2.y; hv[10]=v2.z; hv[11]=v2.w;
        hv[12]=v3.x; hv[13]=v3.y; hv[14]=v3.z; hv[15]=v3.w;
        #pragma unroll
        for (int i = 0; i < 16; ++i) {
            const int e = eb + i;
            const float val = s_o[m * SO + e] + b2[e] + hv[i];
            out[(((size_t)b * E_ + e) * R_ + r) * C_ + c] = val;
        }
    }
}

extern "C" void kernel_launch(void* const* d_in, const int* in_sizes, int n_in,
                              void* d_out, int out_size, void* d_ws, size_t ws_size,
                              hipStream_t stream) {
    const float* x      = (const float*)d_in[0];
    const float* row_wq = (const float*)d_in[1];
    const float* row_bq = (const float*)d_in[2];
    const float* row_wk = (const float*)d_in[3];
    const float* row_bk = (const float*)d_in[4];
    const float* row_wv = (const float*)d_in[5];
    const float* row_bv = (const float*)d_in[6];
    const float* row_wo = (const float*)d_in[7];
    const float* row_bo = (const float*)d_in[8];
    const float* col_wq = (const float*)d_in[9];
    const float* col_bq = (const float*)d_in[10];
    const float* col_wk = (const float*)d_in[11];
    const float* col_bk = (const float*)d_in[12];
    const float* col_wv = (const float*)d_in[13];
    const float* col_bv = (const float*)d_in[14];
    const float* col_wo = (const float*)d_in[15];
    const float* col_bo = (const float*)d_in[16];
    const float* rn_g   = (const float*)d_in[17];
    const float* rn_b   = (const float*)d_in[18];
    const float* cn_g   = (const float*)d_in[19];
    const float* cn_b   = (const float*)d_in[20];
    const float* fn_g   = (const float*)d_in[21];
    const float* fn_b   = (const float*)d_in[22];
    const float* w1     = (const float*)d_in[23];
    const float* b1     = (const float*)d_in[24];
    const float* w2     = (const float*)d_in[25];
    const float* b2     = (const float*)d_in[26];

    const size_t need = (size_t)B_ * C_ * R_ * E_ * sizeof(float);
    if (ws_size < need) return;
    float* hbuf = (float*)d_ws;

    const bool prep = (ws_size >= need + 2 * 16384 * sizeof(short) + 256);
    short* w1b = (short*)((char*)d_ws + need);
    short* w2b = w1b + 16384;

    row_attn<<<dim3(R_, B_), 512, 0, stream>>>(
        x, row_wq, row_bq, row_wk, row_bk, row_wv, row_bv, row_wo, row_bo,
        rn_g, rn_b, hbuf);
    col_attn<<<dim3(C_, B_), 256, 0, stream>>>(
        hbuf, col_wq, col_bq, col_wk, col_bk, col_wv, col_bv, col_wo, col_bo,
        cn_g, cn_b);
    if (prep) {
        prep_weights<<<128, 256, 0, stream>>>(w1, w2, w1b, w2b);
        ffn_mfma<true><<<B_ * R_ * 8, 256, 0, stream>>>(
            hbuf, fn_g, fn_b, w1, w1b, b1, w2, w2b, b2, (float*)d_out);
    } else {
        ffn_mfma<false><<<B_ * R_ * 8, 256, 0, stream>>>(
            hbuf, fn_g, fn_b, w1, w1b, b1, w2, w2b, b2, (float*)d_out);
    }
}

// Round 11
// 1039.800 us; speedup vs baseline: 1.4235x; 1.2649x over previous
//
#include <hip/hip_runtime.h>
#include <cmath>

#define E_ 64
#define H_ 4
#define B_ 2
#define R_ 1225
#define C_ 512
#define EPS 1e-5f

__device__ __forceinline__ float elu1(float a) { return a > 0.f ? a + 1.f : __expf(a); }

typedef float f32x4 __attribute__((ext_vector_type(4)));
typedef short bf16x8 __attribute__((ext_vector_type(8)));
typedef short bf16x4 __attribute__((ext_vector_type(4)));

__device__ __forceinline__ unsigned short f2bf(float f) {
    union { float f; unsigned u; } c; c.f = f;
    unsigned u = c.u + 0x7FFFu + ((c.u >> 16) & 1u);   // RNE
    return (unsigned short)(u >> 16);
}

__device__ __forceinline__ float bf2f(unsigned short s) {
    union { unsigned u; float f; } c; c.u = ((unsigned)s) << 16;
    return c.f;
}

__device__ __forceinline__ bf16x8 pack8(float4 a, float4 b) {
    bf16x8 r;
    r[0] = (short)f2bf(a.x); r[1] = (short)f2bf(a.y);
    r[2] = (short)f2bf(a.z); r[3] = (short)f2bf(a.w);
    r[4] = (short)f2bf(b.x); r[5] = (short)f2bf(b.y);
    r[6] = (short)f2bf(b.z); r[7] = (short)f2bf(b.w);
    return r;
}

// tanh-approx GELU in sigmoid form (max dev ~3e-4 vs exact-erf)
__device__ __forceinline__ float gelu_fast(float a) {
    const float u = a * (-1.5957691216057308f - 0.0713548162726009f * a * a);
    return a / (1.f + __expf(u));
}

// ---------------------------------------------------------------------------
// NEW: hbuf is bf16 in (B, R, C, E) layout.
//  - row_attn writes it CONTIGUOUSLY (thread c -> 128B run, wave -> 8KB)
//  - ffn reads an entire (r, c-block) tile as 8KB contiguous
//  - col_attn reads per-thread 128B chunks at C*E stride (half old bytes)
// Two extra bf16 roundings of the residual stream: absmax 0.031 -> ~0.05,
// threshold 0.113.
// ---------------------------------------------------------------------------

// ---------------------------------------------------------------------------
// Kernel A: row attention, 512 threads, one tile (thread t == position c).
// Structure from round 10; only the h-write changed (bf16 contiguous).
// ---------------------------------------------------------------------------
#define SXR 520   // 512+8 pad

__global__ __launch_bounds__(512, 2) void row_attn(
    const float* __restrict__ x,
    const float* __restrict__ wq, const float* __restrict__ bq,
    const float* __restrict__ wk, const float* __restrict__ bk,
    const float* __restrict__ wv, const float* __restrict__ bv,
    const float* __restrict__ wo, const float* __restrict__ bo,
    const float* __restrict__ lng, const float* __restrict__ lnb,
    short* __restrict__ hout)
{
    const int r = blockIdx.x;
    const int b = blockIdx.y;
    const int t = threadIdx.x;      // 0..511 == c
    const int w = t >> 6;           // wave 0..7
    const int l = t & 63;
    const int lr = l & 15;
    const int lq = l >> 4;

    __shared__ short s_xT[E_][SXR];        // raw x bf16 [e][c]
    __shared__ short s_kb[4][SXR];         // k*rstd bf16
    __shared__ float s_upart[2][H_][E_];   // per-k-half MFMA partials
    __shared__ float s_ktv[E_];
    __shared__ float s_wok[E_][H_];
    __shared__ float s_qm[H_];
    __shared__ float s_sk[H_];
    __shared__ float s_S1[H_];
    __shared__ float red_q[8][H_];
    __shared__ float red_k[8][H_];
    __shared__ float red_k2[8][H_];
    __shared__ float s_cst[16];            // WgQ[4] CQ[4] WgK[4] CK[4]

    if (t < 16) {
        const int h = t & 3;
        const int kind = t >> 2;
        const float* wm = (kind < 2) ? wq : wk;
        const float* vm = (kind & 1) ? lnb : lng;
        float acc = 0.f;
        for (int e = 0; e < E_; ++e) acc += wm[h * E_ + e] * vm[e];
        s_cst[t] = acc;
    }
    __syncthreads();

    const size_t RC = (size_t)R_ * C_;
    const float* xbase = x + (size_t)b * E_ * RC + (size_t)r * C_;

    float qs[H_];
    float aq[H_], ak[H_], ak2[H_];
    {
        const float* xp = xbase + t;
        float s = 0.f, ss = 0.f;
        float dq[H_] = {0.f, 0.f, 0.f, 0.f};
        float dk[H_] = {0.f, 0.f, 0.f, 0.f};
        #pragma unroll 16
        for (int e = 0; e < E_; ++e) {
            const float xv = xp[(size_t)e * RC];
            s += xv; ss += xv * xv;
            const float t1 = lng[e] * xv;
            #pragma unroll
            for (int h = 0; h < H_; ++h) { dq[h] += wq[h * E_ + e] * t1; dk[h] += wk[h * E_ + e] * t1; }
            s_xT[e][t] = (short)f2bf(xv);
        }
        const float mu = s * (1.f / E_);
        const float rstd = rsqrtf(ss * (1.f / E_) - mu * mu + EPS);
        const float mr = mu * rstd;
        #pragma unroll
        for (int h = 0; h < H_; ++h) {
            const float qv = elu1(rstd * dq[h] - mr * s_cst[h]     + s_cst[4 + h]  + bq[h]);
            const float kv = elu1(rstd * dk[h] - mr * s_cst[8 + h] + s_cst[12 + h] + bk[h]);
            qs[h] = qv;
            aq[h] = qv; ak[h] = kv; ak2[h] = kv * mr;
            s_kb[h][t] = (short)f2bf(kv * rstd);
        }
    }
    __syncthreads();

    // MFMA: u = K^T x X, K=512 split across wave pairs
    {
        const int et = w & 3;
        const int kh = w >> 2;
        f32x4 uacc; uacc[0] = uacc[1] = uacc[2] = uacc[3] = 0.f;
        #pragma unroll
        for (int ks = 0; ks < 8; ++ks) {
            const int co = kh * 256 + ks * 32 + lq * 8;
            bf16x8 af;
            #pragma unroll
            for (int i = 0; i < 8; ++i) af[i] = 0;
            if (lr < 4) af = *reinterpret_cast<const bf16x8*>(&s_kb[lr][co]);
            const bf16x8 bf = *reinterpret_cast<const bf16x8*>(&s_xT[et * 16 + lr][co]);
            uacc = __builtin_amdgcn_mfma_f32_16x16x32_bf16(af, bf, uacc, 0, 0, 0);
        }
        if (lq == 0) {
            #pragma unroll
            for (int i = 0; i < 4; ++i) s_upart[kh][i][et * 16 + lr] = uacc[i];
        }
    }

    #pragma unroll
    for (int h = 0; h < H_; ++h) {
        #pragma unroll
        for (int off = 32; off; off >>= 1) {
            aq[h] += __shfl_xor(aq[h], off, 64);
            ak[h] += __shfl_xor(ak[h], off, 64);
            ak2[h] += __shfl_xor(ak2[h], off, 64);
        }
    }
    if (l == 0) {
        #pragma unroll
        for (int h = 0; h < H_; ++h) { red_q[w][h] = aq[h]; red_k[w][h] = ak[h]; red_k2[w][h] = ak2[h]; }
    }
    __syncthreads();
    if (t < H_) {
        float sq = 0.f, sk = 0.f, s1 = 0.f;
        #pragma unroll
        for (int w2 = 0; w2 < 8; ++w2) { sq += red_q[w2][t]; sk += red_k[w2][t]; s1 += red_k2[w2][t]; }
        s_qm[t] = sq * (1.f / C_);
        s_sk[t] = sk;
        s_S1[t] = s1;
    }
    __syncthreads();
    if (t < H_ * E_) {
        const int h = t >> 6, e = t & 63;
        const float m1 = s_upart[0][h][e] + s_upart[1][h][e];
        s_upart[0][h][e] = lng[e] * (m1 - s_S1[h]) + lnb[e] * s_sk[h];
    }
    __syncthreads();
    if (t < E_) {
        const int h = t >> 4;
        float acc = 0.f;
        #pragma unroll
        for (int e = 0; e < E_; ++e) acc += wv[t * E_ + e] * s_upart[0][h][e];
        s_ktv[t] = acc / s_sk[h] + bv[t];
    }
    __syncthreads();
    if (t < E_) {
        #pragma unroll
        for (int h = 0; h < H_; ++h) {
            float acc = 0.f;
            #pragma unroll
            for (int d = 0; d < 16; ++d) acc += wo[t * E_ + h * 16 + d] * s_ktv[h * 16 + d];
            s_wok[t][h] = acc;
        }
    }
    __syncthreads();

    // phase E: residual from LDS + CONTIGUOUS bf16 h-write
    {
        float qn[H_];
        #pragma unroll
        for (int h = 0; h < H_; ++h) qn[h] = qs[h] / s_qm[h];
        short* hp = hout + ((size_t)((size_t)b * R_ + r) * C_ + t) * E_;
        #pragma unroll
        for (int e8 = 0; e8 < 8; ++e8) {
            bf16x8 o;
            #pragma unroll
            for (int i = 0; i < 8; ++i) {
                const int e = e8 * 8 + i;
                float tt = bo[e];
                #pragma unroll
                for (int h = 0; h < H_; ++h) tt += qn[h] * s_wok[e][h];
                o[i] = (short)f2bf(bf2f((unsigned short)s_xT[e][t]) + tt);
            }
            *reinterpret_cast<bf16x8*>(hp + e8 * 8) = o;
        }
    }
}

// ---------------------------------------------------------------------------
// Kernel B: col attention over r for each (b, c). In-place on bf16 hbuf.
// Per-thread 128B chunks at C*E stride (half old bytes); s_xT direct copies.
// ---------------------------------------------------------------------------
#define SX 264

__global__ __launch_bounds__(256, 3) void col_attn(
    short* __restrict__ hbuf,
    const float* __restrict__ wq, const float* __restrict__ bq,
    const float* __restrict__ wk, const float* __restrict__ bk,
    const float* __restrict__ wv, const float* __restrict__ bv,
    const float* __restrict__ wo, const float* __restrict__ bo,
    const float* __restrict__ lng, const float* __restrict__ lnb)
{
    const int c = blockIdx.x;
    const int b = blockIdx.y;
    const int t = threadIdx.x;
    const int w = t >> 6;
    const int l = t & 63;
    const int lr = l & 15;
    const int lq = l >> 4;

    __shared__ short s_xT[E_][SX];
    __shared__ short s_kb[4][SX];
    __shared__ float s_u[H_][E_];
    __shared__ float s_ktv[E_];
    __shared__ float s_wok[E_][H_];
    __shared__ float s_qm[H_];
    __shared__ float s_sk[H_];
    __shared__ float s_S1[H_];
    __shared__ float red_q[4][H_];
    __shared__ float red_k[4][H_];
    __shared__ float red_k2[4][H_];
    __shared__ float s_cst[16];

    if (t < 16) {
        const int h = t & 3;
        const int kind = t >> 2;
        const float* wm = (kind < 2) ? wq : wk;
        const float* vm = (kind & 1) ? lnb : lng;
        float acc = 0.f;
        for (int e = 0; e < E_; ++e) acc += wm[h * E_ + e] * vm[e];
        s_cst[t] = acc;
    }
    __syncthreads();

    const size_t CE = (size_t)C_ * E_;
    short* hp0 = hbuf + (size_t)b * R_ * CE + (size_t)c * E_;

    float aq[H_]  = {0.f, 0.f, 0.f, 0.f};
    float ak[H_]  = {0.f, 0.f, 0.f, 0.f};
    float ak2[H_] = {0.f, 0.f, 0.f, 0.f};
    unsigned qs_pk[5][2];
    f32x4 uacc; uacc[0] = uacc[1] = uacc[2] = uacc[3] = 0.f;

    #pragma unroll 1
    for (int it = 0; it < 5; ++it) {
        const int rr = it * 256 + t;
        if (rr < R_) {
            const short* pp = hp0 + (size_t)rr * CE;
            bf16x8 hv8[8];
            #pragma unroll
            for (int g = 0; g < 8; ++g) hv8[g] = *reinterpret_cast<const bf16x8*>(pp + g * 8);
            float s = 0.f, ss = 0.f;
            float dq[H_] = {0.f, 0.f, 0.f, 0.f};
            float dk[H_] = {0.f, 0.f, 0.f, 0.f};
            #pragma unroll
            for (int g = 0; g < 8; ++g) {
                #pragma unroll
                for (int i = 0; i < 8; ++i) {
                    const int e = g * 8 + i;
                    const float xv = bf2f((unsigned short)hv8[g][i]);
                    s += xv; ss += xv * xv;
                    const float t1 = lng[e] * xv;
                    #pragma unroll
                    for (int h = 0; h < H_; ++h) { dq[h] += wq[h * E_ + e] * t1; dk[h] += wk[h * E_ + e] * t1; }
                    s_xT[e][t] = hv8[g][i];
                }
            }
            const float mu = s * (1.f / E_);
            const float rstd = rsqrtf(ss * (1.f / E_) - mu * mu + EPS);
            const float mr = mu * rstd;
            float qv[H_];
            #pragma unroll
            for (int h = 0; h < H_; ++h) {
                qv[h] = elu1(rstd * dq[h] - mr * s_cst[h]     + s_cst[4 + h]  + bq[h]);
                const float kv = elu1(rstd * dk[h] - mr * s_cst[8 + h] + s_cst[12 + h] + bk[h]);
                aq[h] += qv[h]; ak[h] += kv; ak2[h] += kv * mr;
                s_kb[h][t] = (short)f2bf(kv * rstd);
            }
            qs_pk[it][0] = ((unsigned)f2bf(qv[1]) << 16) | f2bf(qv[0]);
            qs_pk[it][1] = ((unsigned)f2bf(qv[3]) << 16) | f2bf(qv[2]);
        } else {
            #pragma unroll
            for (int e = 0; e < E_; ++e) s_xT[e][t] = 0;
            #pragma unroll
            for (int h = 0; h < H_; ++h) s_kb[h][t] = 0;
            qs_pk[it][0] = 0; qs_pk[it][1] = 0;
        }
        __syncthreads();
        #pragma unroll
        for (int ks = 0; ks < 8; ++ks) {
            bf16x8 af;
            #pragma unroll
            for (int i = 0; i < 8; ++i) af[i] = 0;
            if (lr < 4) af = *reinterpret_cast<const bf16x8*>(&s_kb[lr][ks * 32 + lq * 8]);
            const bf16x8 bf = *reinterpret_cast<const bf16x8*>(&s_xT[w * 16 + lr][ks * 32 + lq * 8]);
            uacc = __builtin_amdgcn_mfma_f32_16x16x32_bf16(af, bf, uacc, 0, 0, 0);
        }
        __syncthreads();
    }

    #pragma unroll
    for (int h = 0; h < H_; ++h) {
        #pragma unroll
        for (int off = 32; off; off >>= 1) {
            aq[h] += __shfl_xor(aq[h], off, 64);
            ak[h] += __shfl_xor(ak[h], off, 64);
            ak2[h] += __shfl_xor(ak2[h], off, 64);
        }
    }
    if (l == 0) {
        #pragma unroll
        for (int h = 0; h < H_; ++h) { red_q[w][h] = aq[h]; red_k[w][h] = ak[h]; red_k2[w][h] = ak2[h]; }
    }
    __syncthreads();
    if (t < H_) {
        float sq = 0.f, sk = 0.f, s1 = 0.f;
        #pragma unroll
        for (int w2 = 0; w2 < 4; ++w2) { sq += red_q[w2][t]; sk += red_k[w2][t]; s1 += red_k2[w2][t]; }
        s_qm[t] = sq * (1.f / R_);
        s_sk[t] = sk;
        s_S1[t] = s1;
    }
    __syncthreads();
    if (lq == 0) {
        const int e = w * 16 + lr;
        #pragma unroll
        for (int i = 0; i < 4; ++i)
            s_u[i][e] = lng[e] * (uacc[i] - s_S1[i]) + lnb[e] * s_sk[i];
    }
    __syncthreads();
    if (t < E_) {
        const int h = t >> 4;
        float acc = 0.f;
        #pragma unroll
        for (int e = 0; e < E_; ++e) acc += wv[t * E_ + e] * s_u[h][e];
        s_ktv[t] = acc / s_sk[h] + bv[t];
    }
    __syncthreads();
    if (t < E_) {
        #pragma unroll
        for (int h = 0; h < H_; ++h) {
            float acc = 0.f;
            #pragma unroll
            for (int d = 0; d < 16; ++d) acc += wo[t * E_ + h * 16 + d] * s_ktv[h * 16 + d];
            s_wok[t][h] = acc;
        }
    }
    __syncthreads();

    #pragma unroll 1
    for (int it = 0; it < 5; ++it) {
        const int rr = it * 256 + t;
        if (rr >= R_) continue;
        float qn[H_];
        qn[0] = bf2f((unsigned short)(qs_pk[it][0] & 0xFFFF)) / s_qm[0];
        qn[1] = bf2f((unsigned short)(qs_pk[it][0] >> 16))    / s_qm[1];
        qn[2] = bf2f((unsigned short)(qs_pk[it][1] & 0xFFFF)) / s_qm[2];
        qn[3] = bf2f((unsigned short)(qs_pk[it][1] >> 16))    / s_qm[3];
        short* pp = hp0 + (size_t)rr * CE;
        #pragma unroll
        for (int g = 0; g < 8; ++g) {
            const bf16x8 v = *reinterpret_cast<const bf16x8*>(pp + g * 8);
            bf16x8 o;
            #pragma unroll
            for (int i = 0; i < 8; ++i) {
                const int e = g * 8 + i;
                float tt = bo[e];
                #pragma unroll
                for (int h = 0; h < H_; ++h) tt += qn[h] * s_wok[e][h];
                o[i] = (short)f2bf(bf2f((unsigned short)v[i]) + tt);
            }
            *reinterpret_cast<bf16x8*>(pp + g * 8) = o;
        }
    }
}

// ---------------------------------------------------------------------------
// prep_weights: fp32 -> bf16 for w1/w2.
// ---------------------------------------------------------------------------
__global__ __launch_bounds__(256) void prep_weights(
    const float* __restrict__ w1, const float* __restrict__ w2,
    short* __restrict__ w1b, short* __restrict__ w2b)
{
    const int i = blockIdx.x * 256 + threadIdx.x;
    if (i < 16384) w1b[i] = (short)f2bf(w1[i]);
    else           w2b[i - 16384] = (short)f2bf(w2[i - 16384]);
}

// ---------------------------------------------------------------------------
// Kernel C: MFMA bf16 FFN. hbuf tile (r, c0..c0+63, all e) is 8KB CONTIGUOUS.
// ---------------------------------------------------------------------------
#define SA 72
#define SG 264
#define SO 65

template <bool PREP>
__global__ __launch_bounds__(256) void ffn_mfma(
    const short* __restrict__ hbuf,
    const float* __restrict__ lng, const float* __restrict__ lnb,
    const float* __restrict__ w1, const short* __restrict__ w1b,
    const float* __restrict__ b1,
    const float* __restrict__ w2, const short* __restrict__ w2b,
    const float* __restrict__ b2,
    float* __restrict__ out)
{
    __shared__ __align__(16) char smem[33792 + 16640];
    short* s_g = (short*)smem;
    short* s_a = (short*)(smem + 33792);
    float* s_o = (float*)(smem + 33792);

    const int t = threadIdx.x;
    const int w = t >> 6;
    const int l = t & 63;
    const int lr = l & 15;
    const int lq = l >> 4;

    const int bid = blockIdx.x;
    const int cb  = bid & 7;
    const int rem = bid >> 3;
    const int r   = rem % R_;
    const int b   = rem / R_;
    const int c0  = cb * 64;

    const short* tile = hbuf + ((size_t)((size_t)b * R_ + r) * C_ + c0) * E_;

    // phase 1: coalesced 8KB tile read (32B/lane), LN, bf16 -> s_a[m][e]
    {
        const int m  = t >> 2;     // position (c offset)
        const int qi = t & 3;      // 16-element quarter
        const short* hp = tile + (size_t)t * 16;
        const bf16x8 v0 = *reinterpret_cast<const bf16x8*>(hp);
        const bf16x8 v1 = *reinterpret_cast<const bf16x8*>(hp + 8);
        float hv[16];
        #pragma unroll
        for (int i = 0; i < 8; ++i) { hv[i] = bf2f((unsigned short)v0[i]); hv[8 + i] = bf2f((unsigned short)v1[i]); }
        float s = 0.f, ss = 0.f;
        #pragma unroll
        for (int i = 0; i < 16; ++i) { s += hv[i]; ss += hv[i] * hv[i]; }
        s  += __shfl_xor(s, 1, 64);  s  += __shfl_xor(s, 2, 64);
        ss += __shfl_xor(ss, 1, 64); ss += __shfl_xor(ss, 2, 64);
        const float mu = s * (1.f / 64.f);
        const float rstd = rsqrtf(ss * (1.f / 64.f) - mu * mu + EPS);
        bf16x8 o0, o1;
        #pragma unroll
        for (int i = 0; i < 8; ++i) {
            const int e = qi * 16 + i;
            o0[i] = (short)f2bf((hv[i] - mu) * rstd * lng[e] + lnb[e]);
        }
        #pragma unroll
        for (int i = 0; i < 8; ++i) {
            const int e = qi * 16 + 8 + i;
            o1[i] = (short)f2bf((hv[8 + i] - mu) * rstd * lng[e] + lnb[e]);
        }
        *reinterpret_cast<bf16x8*>(&s_a[m * SA + qi * 16])     = o0;
        *reinterpret_cast<bf16x8*>(&s_a[m * SA + qi * 16 + 8]) = o1;
    }
    __syncthreads();

    // GEMM1 (swapped): D1T = W1 x XN^T, GELU -> s_g
    {
        bf16x8 bfr[4][2];
        #pragma unroll
        for (int mt = 0; mt < 4; ++mt)
            #pragma unroll
            for (int ks = 0; ks < 2; ++ks)
                bfr[mt][ks] = *reinterpret_cast<const bf16x8*>(
                    &s_a[(mt * 16 + lr) * SA + ks * 32 + lq * 8]);

        #pragma unroll
        for (int nn = 0; nn < 4; ++nn) {
            const int jt = w * 4 + nn;
            bf16x8 afr[2];
            if (PREP) {
                #pragma unroll
                for (int ks = 0; ks < 2; ++ks)
                    afr[ks] = *reinterpret_cast<const bf16x8*>(
                        w1b + (size_t)(jt * 16 + lr) * 64 + ks * 32 + lq * 8);
            } else {
                #pragma unroll
                for (int ks = 0; ks < 2; ++ks) {
                    const float4* wp = (const float4*)(w1 + (size_t)(jt * 16 + lr) * 64 + ks * 32 + lq * 8);
                    afr[ks] = pack8(wp[0], wp[1]);
                }
            }
            f32x4 acc[4];
            #pragma unroll
            for (int mt = 0; mt < 4; ++mt) { acc[mt][0]=0.f; acc[mt][1]=0.f; acc[mt][2]=0.f; acc[mt][3]=0.f; }
            #pragma unroll
            for (int ks = 0; ks < 2; ++ks)
                #pragma unroll
                for (int mt = 0; mt < 4; ++mt)
                    acc[mt] = __builtin_amdgcn_mfma_f32_16x16x32_bf16(afr[ks], bfr[mt][ks], acc[mt], 0, 0, 0);

            const float4 b1v = *reinterpret_cast<const float4*>(&b1[jt * 16 + lq * 4]);
            const float* b1p = (const float*)&b1v;
            #pragma unroll
            for (int mt = 0; mt < 4; ++mt) {
                const int m = mt * 16 + lr;
                bf16x4 pk;
                #pragma unroll
                for (int i = 0; i < 4; ++i) {
                    const float aa = acc[mt][i] + b1p[i];
                    pk[i] = (short)f2bf(gelu_fast(aa));
                }
                *reinterpret_cast<bf16x4*>(&s_g[m * SG + jt * 16 + lq * 4]) = pk;
            }
        }
    }
    __syncthreads();

    // GEMM2: D2 = G x w2^T
    {
        f32x4 acc2[4];
        #pragma unroll
        for (int mt = 0; mt < 4; ++mt) { acc2[mt][0]=0.f; acc2[mt][1]=0.f; acc2[mt][2]=0.f; acc2[mt][3]=0.f; }
        const int n = w * 16 + lr;
        #pragma unroll
        for (int ks = 0; ks < 8; ++ks) {
            bf16x8 bfr;
            if (PREP) {
                bfr = *reinterpret_cast<const bf16x8*>(w2b + (size_t)n * 256 + ks * 32 + lq * 8);
            } else {
                const float4* wp = (const float4*)(w2 + (size_t)n * 256 + ks * 32 + lq * 8);
                bfr = pack8(wp[0], wp[1]);
            }
            #pragma unroll
            for (int mt = 0; mt < 4; ++mt) {
                const bf16x8 af = *reinterpret_cast<const bf16x8*>(
                    &s_g[(mt * 16 + lr) * SG + ks * 32 + lq * 8]);
                acc2[mt] = __builtin_amdgcn_mfma_f32_16x16x32_bf16(af, bfr, acc2[mt], 0, 0, 0);
            }
        }
        #pragma unroll
        for (int mt = 0; mt < 4; ++mt)
            #pragma unroll
            for (int i = 0; i < 4; ++i)
                s_o[(mt * 16 + lq * 4 + i) * SO + n] = acc2[mt][i];
    }
    __syncthreads();

    // store: residual (L1-hot re-read of bf16 tile) + b2, coalesced along c
    {
        const int m  = t & 63;
        const int eb = (t >> 6) * 16;
        const int c  = c0 + m;
        const short* hp = tile + (size_t)m * E_ + eb;
        const bf16x8 v0 = *reinterpret_cast<const bf16x8*>(hp);
        const bf16x8 v1 = *reinterpret_cast<const bf16x8*>(hp + 8);
        const size_t RC = (size_t)R_ * C_;
        float* op = out + (size_t)b * E_ * RC + (size_t)r * C_ + c;
        #pragma unroll
        for (int i = 0; i < 16; ++i) {
            const int e = eb + i;
            const float hvv = bf2f((unsigned short)(i < 8 ? v0[i] : v1[i - 8]));
            op[(size_t)e * RC] = s_o[m * SO + e] + b2[e] + hvv;
        }
    }
}

extern "C" void kernel_launch(void* const* d_in, const int* in_sizes, int n_in,
                              void* d_out, int out_size, void* d_ws, size_t ws_size,
                              hipStream_t stream) {
    const float* x      = (const float*)d_in[0];
    const float* row_wq = (const float*)d_in[1];
    const float* row_bq = (const float*)d_in[2];
    const float* row_wk = (const float*)d_in[3];
    const float* row_bk = (const float*)d_in[4];
    const float* row_wv = (const float*)d_in[5];
    const float* row_bv = (const float*)d_in[6];
    const float* row_wo = (const float*)d_in[7];
    const float* row_bo = (const float*)d_in[8];
    const float* col_wq = (const float*)d_in[9];
    const float* col_bq = (const float*)d_in[10];
    const float* col_wk = (const float*)d_in[11];
    const float* col_bk = (const float*)d_in[12];
    const float* col_wv = (const float*)d_in[13];
    const float* col_bv = (const float*)d_in[14];
    const float* col_wo = (const float*)d_in[15];
    const float* col_bo = (const float*)d_in[16];
    const float* rn_g   = (const float*)d_in[17];
    const float* rn_b   = (const float*)d_in[18];
    const float* cn_g   = (const float*)d_in[19];
    const float* cn_b   = (const float*)d_in[20];
    const float* fn_g   = (const float*)d_in[21];
    const float* fn_b   = (const float*)d_in[22];
    const float* w1     = (const float*)d_in[23];
    const float* b1     = (const float*)d_in[24];
    const float* w2     = (const float*)d_in[25];
    const float* b2     = (const float*)d_in[26];

    const size_t need = (size_t)B_ * R_ * C_ * E_ * sizeof(short);
    if (ws_size < need) return;
    short* hbuf = (short*)d_ws;

    const bool prep = (ws_size >= need + 2 * 16384 * sizeof(short) + 256);
    short* w1b = (short*)((char*)d_ws + need);
    short* w2b = w1b + 16384;

    row_attn<<<dim3(R_, B_), 512, 0, stream>>>(
        x, row_wq, row_bq, row_wk, row_bk, row_wv, row_bv, row_wo, row_bo,
        rn_g, rn_b, hbuf);
    col_attn<<<dim3(C_, B_), 256, 0, stream>>>(
        hbuf, col_wq, col_bq, col_wk, col_bk, col_wv, col_bv, col_wo, col_bo,
        cn_g, cn_b);
    if (prep) {
        prep_weights<<<128, 256, 0, stream>>>(w1, w2, w1b, w2b);
        ffn_mfma<true><<<B_ * R_ * 8, 256, 0, stream>>>(
            hbuf, fn_g, fn_b, w1, w1b, b1, w2, w2b, b2, (float*)d_out);
    } else {
        ffn_mfma<false><<<B_ * R_ * 8, 256, 0, stream>>>(
            hbuf, fn_g, fn_b, w1, w1b, b1, w2, w2b, b2, (float*)d_out);
    }
}

// Round 12
// 876.459 us; speedup vs baseline: 1.6888x; 1.1864x over previous
//
#include <hip/hip_runtime.h>
#include <cmath>

#define E_ 64
#define H_ 4
#define B_ 2
#define R_ 1225
#define C_ 512
#define EPS 1e-5f

__device__ __forceinline__ float elu1(float a) { return a > 0.f ? a + 1.f : __expf(a); }

typedef float f32x4 __attribute__((ext_vector_type(4)));
typedef short bf16x8 __attribute__((ext_vector_type(8)));
typedef short bf16x4 __attribute__((ext_vector_type(4)));

__device__ __forceinline__ unsigned short f2bf(float f) {
    union { float f; unsigned u; } c; c.f = f;
    unsigned u = c.u + 0x7FFFu + ((c.u >> 16) & 1u);   // RNE
    return (unsigned short)(u >> 16);
}

__device__ __forceinline__ float bf2f(unsigned short s) {
    union { unsigned u; float f; } c; c.u = ((unsigned)s) << 16;
    return c.f;
}

__device__ __forceinline__ bf16x8 pack8(float4 a, float4 b) {
    bf16x8 r;
    r[0] = (short)f2bf(a.x); r[1] = (short)f2bf(a.y);
    r[2] = (short)f2bf(a.z); r[3] = (short)f2bf(a.w);
    r[4] = (short)f2bf(b.x); r[5] = (short)f2bf(b.y);
    r[6] = (short)f2bf(b.z); r[7] = (short)f2bf(b.w);
    return r;
}

// tanh-approx GELU in sigmoid form (max dev ~3e-4 vs exact-erf)
__device__ __forceinline__ float gelu_fast(float a) {
    const float u = a * (-1.5957691216057308f - 0.0713548162726009f * a * a);
    return a / (1.f + __expf(u));
}

// ---------------------------------------------------------------------------
// Pipeline (round 12):
//  row_attn  : x -> h (bf16, (B,R,C,E), contiguous write)     [unchanged r11]
//  col_stats : h -> per-(b,c) stats only (NO h rewrite):
//                qbuf (B,C,R,4) bf16  = q values (contiguous write)
//                wokq (B,C,E,H) fp32  = wok/qm (L2-resident, 1MB)
//  ffn_mfma  : applies col-attn inline (hcol = h + col_bo + q.wokq) before
//              LN (phase 1) and as residual (store phase), then FFN.
// Removes col pass-2's 160MB read + 160MB RMW write (3.3x-amplified).
// ---------------------------------------------------------------------------

#define SXR 520   // 512+8 pad

__global__ __launch_bounds__(512, 2) void row_attn(
    const float* __restrict__ x,
    const float* __restrict__ wq, const float* __restrict__ bq,
    const float* __restrict__ wk, const float* __restrict__ bk,
    const float* __restrict__ wv, const float* __restrict__ bv,
    const float* __restrict__ wo, const float* __restrict__ bo,
    const float* __restrict__ lng, const float* __restrict__ lnb,
    short* __restrict__ hout)
{
    const int r = blockIdx.x;
    const int b = blockIdx.y;
    const int t = threadIdx.x;      // 0..511 == c
    const int w = t >> 6;
    const int l = t & 63;
    const int lr = l & 15;
    const int lq = l >> 4;

    __shared__ short s_xT[E_][SXR];
    __shared__ short s_kb[4][SXR];
    __shared__ float s_upart[2][H_][E_];
    __shared__ float s_ktv[E_];
    __shared__ float s_wok[E_][H_];
    __shared__ float s_qm[H_];
    __shared__ float s_sk[H_];
    __shared__ float s_S1[H_];
    __shared__ float red_q[8][H_];
    __shared__ float red_k[8][H_];
    __shared__ float red_k2[8][H_];
    __shared__ float s_cst[16];

    if (t < 16) {
        const int h = t & 3;
        const int kind = t >> 2;
        const float* wm = (kind < 2) ? wq : wk;
        const float* vm = (kind & 1) ? lnb : lng;
        float acc = 0.f;
        for (int e = 0; e < E_; ++e) acc += wm[h * E_ + e] * vm[e];
        s_cst[t] = acc;
    }
    __syncthreads();

    const size_t RC = (size_t)R_ * C_;
    const float* xbase = x + (size_t)b * E_ * RC + (size_t)r * C_;

    float qs[H_];
    float aq[H_], ak[H_], ak2[H_];
    {
        const float* xp = xbase + t;
        float s = 0.f, ss = 0.f;
        float dq[H_] = {0.f, 0.f, 0.f, 0.f};
        float dk[H_] = {0.f, 0.f, 0.f, 0.f};
        #pragma unroll 16
        for (int e = 0; e < E_; ++e) {
            const float xv = xp[(size_t)e * RC];
            s += xv; ss += xv * xv;
            const float t1 = lng[e] * xv;
            #pragma unroll
            for (int h = 0; h < H_; ++h) { dq[h] += wq[h * E_ + e] * t1; dk[h] += wk[h * E_ + e] * t1; }
            s_xT[e][t] = (short)f2bf(xv);
        }
        const float mu = s * (1.f / E_);
        const float rstd = rsqrtf(ss * (1.f / E_) - mu * mu + EPS);
        const float mr = mu * rstd;
        #pragma unroll
        for (int h = 0; h < H_; ++h) {
            const float qv = elu1(rstd * dq[h] - mr * s_cst[h]     + s_cst[4 + h]  + bq[h]);
            const float kv = elu1(rstd * dk[h] - mr * s_cst[8 + h] + s_cst[12 + h] + bk[h]);
            qs[h] = qv;
            aq[h] = qv; ak[h] = kv; ak2[h] = kv * mr;
            s_kb[h][t] = (short)f2bf(kv * rstd);
        }
    }
    __syncthreads();

    {
        const int et = w & 3;
        const int kh = w >> 2;
        f32x4 uacc; uacc[0] = uacc[1] = uacc[2] = uacc[3] = 0.f;
        #pragma unroll
        for (int ks = 0; ks < 8; ++ks) {
            const int co = kh * 256 + ks * 32 + lq * 8;
            bf16x8 af;
            #pragma unroll
            for (int i = 0; i < 8; ++i) af[i] = 0;
            if (lr < 4) af = *reinterpret_cast<const bf16x8*>(&s_kb[lr][co]);
            const bf16x8 bf = *reinterpret_cast<const bf16x8*>(&s_xT[et * 16 + lr][co]);
            uacc = __builtin_amdgcn_mfma_f32_16x16x32_bf16(af, bf, uacc, 0, 0, 0);
        }
        if (lq == 0) {
            #pragma unroll
            for (int i = 0; i < 4; ++i) s_upart[kh][i][et * 16 + lr] = uacc[i];
        }
    }

    #pragma unroll
    for (int h = 0; h < H_; ++h) {
        #pragma unroll
        for (int off = 32; off; off >>= 1) {
            aq[h] += __shfl_xor(aq[h], off, 64);
            ak[h] += __shfl_xor(ak[h], off, 64);
            ak2[h] += __shfl_xor(ak2[h], off, 64);
        }
    }
    if (l == 0) {
        #pragma unroll
        for (int h = 0; h < H_; ++h) { red_q[w][h] = aq[h]; red_k[w][h] = ak[h]; red_k2[w][h] = ak2[h]; }
    }
    __syncthreads();
    if (t < H_) {
        float sq = 0.f, sk = 0.f, s1 = 0.f;
        #pragma unroll
        for (int w2 = 0; w2 < 8; ++w2) { sq += red_q[w2][t]; sk += red_k[w2][t]; s1 += red_k2[w2][t]; }
        s_qm[t] = sq * (1.f / C_);
        s_sk[t] = sk;
        s_S1[t] = s1;
    }
    __syncthreads();
    if (t < H_ * E_) {
        const int h = t >> 6, e = t & 63;
        const float m1 = s_upart[0][h][e] + s_upart[1][h][e];
        s_upart[0][h][e] = lng[e] * (m1 - s_S1[h]) + lnb[e] * s_sk[h];
    }
    __syncthreads();
    if (t < E_) {
        const int h = t >> 4;
        float acc = 0.f;
        #pragma unroll
        for (int e = 0; e < E_; ++e) acc += wv[t * E_ + e] * s_upart[0][h][e];
        s_ktv[t] = acc / s_sk[h] + bv[t];
    }
    __syncthreads();
    if (t < E_) {
        #pragma unroll
        for (int h = 0; h < H_; ++h) {
            float acc = 0.f;
            #pragma unroll
            for (int d = 0; d < 16; ++d) acc += wo[t * E_ + h * 16 + d] * s_ktv[h * 16 + d];
            s_wok[t][h] = acc;
        }
    }
    __syncthreads();

    {
        float qn[H_];
        #pragma unroll
        for (int h = 0; h < H_; ++h) qn[h] = qs[h] / s_qm[h];
        short* hp = hout + ((size_t)((size_t)b * R_ + r) * C_ + t) * E_;
        #pragma unroll
        for (int e8 = 0; e8 < 8; ++e8) {
            bf16x8 o;
            #pragma unroll
            for (int i = 0; i < 8; ++i) {
                const int e = e8 * 8 + i;
                float tt = bo[e];
                #pragma unroll
                for (int h = 0; h < H_; ++h) tt += qn[h] * s_wok[e][h];
                o[i] = (short)f2bf(bf2f((unsigned short)s_xT[e][t]) + tt);
            }
            *reinterpret_cast<bf16x8*>(hp + e8 * 8) = o;
        }
    }
}

// ---------------------------------------------------------------------------
// col_stats: col-attention pass 1 only. Reads h (bf16, (B,R,C,E)); computes
// per-(b,c) wokq = wok/qm (fp32) and per-position q (bf16, (B,C,R,4)).
// NO h rewrite. (bo folded into ffn.)
// ---------------------------------------------------------------------------
#define SX 264

__global__ __launch_bounds__(256, 3) void col_stats(
    const short* __restrict__ hbuf,
    const float* __restrict__ wq, const float* __restrict__ bq,
    const float* __restrict__ wk, const float* __restrict__ bk,
    const float* __restrict__ wv, const float* __restrict__ bv,
    const float* __restrict__ wo,
    const float* __restrict__ lng, const float* __restrict__ lnb,
    unsigned short* __restrict__ qbuf, float* __restrict__ wokq)
{
    const int c = blockIdx.x;
    const int b = blockIdx.y;
    const int t = threadIdx.x;
    const int w = t >> 6;
    const int l = t & 63;
    const int lr = l & 15;
    const int lq = l >> 4;

    __shared__ short s_xT[E_][SX];
    __shared__ short s_kb[4][SX];
    __shared__ float s_u[H_][E_];
    __shared__ float s_ktv[E_];
    __shared__ float s_wok[E_][H_];
    __shared__ float s_qm[H_];
    __shared__ float s_sk[H_];
    __shared__ float s_S1[H_];
    __shared__ float red_q[4][H_];
    __shared__ float red_k[4][H_];
    __shared__ float red_k2[4][H_];
    __shared__ float s_cst[16];

    if (t < 16) {
        const int h = t & 3;
        const int kind = t >> 2;
        const float* wm = (kind < 2) ? wq : wk;
        const float* vm = (kind & 1) ? lnb : lng;
        float acc = 0.f;
        for (int e = 0; e < E_; ++e) acc += wm[h * E_ + e] * vm[e];
        s_cst[t] = acc;
    }
    __syncthreads();

    const size_t CE = (size_t)C_ * E_;
    const short* hp0 = hbuf + (size_t)b * R_ * CE + (size_t)c * E_;
    unsigned short* qb0 = qbuf + ((size_t)(b * C_ + c)) * R_ * 4;

    float aq[H_]  = {0.f, 0.f, 0.f, 0.f};
    float ak[H_]  = {0.f, 0.f, 0.f, 0.f};
    float ak2[H_] = {0.f, 0.f, 0.f, 0.f};
    f32x4 uacc; uacc[0] = uacc[1] = uacc[2] = uacc[3] = 0.f;

    #pragma unroll 1
    for (int it = 0; it < 5; ++it) {
        const int rr = it * 256 + t;
        if (rr < R_) {
            const short* pp = hp0 + (size_t)rr * CE;
            bf16x8 hv8[8];
            #pragma unroll
            for (int g = 0; g < 8; ++g) hv8[g] = *reinterpret_cast<const bf16x8*>(pp + g * 8);
            float s = 0.f, ss = 0.f;
            float dq[H_] = {0.f, 0.f, 0.f, 0.f};
            float dk[H_] = {0.f, 0.f, 0.f, 0.f};
            #pragma unroll
            for (int g = 0; g < 8; ++g) {
                #pragma unroll
                for (int i = 0; i < 8; ++i) {
                    const int e = g * 8 + i;
                    const float xv = bf2f((unsigned short)hv8[g][i]);
                    s += xv; ss += xv * xv;
                    const float t1 = lng[e] * xv;
                    #pragma unroll
                    for (int h = 0; h < H_; ++h) { dq[h] += wq[h * E_ + e] * t1; dk[h] += wk[h * E_ + e] * t1; }
                    s_xT[e][t] = hv8[g][i];
                }
            }
            const float mu = s * (1.f / E_);
            const float rstd = rsqrtf(ss * (1.f / E_) - mu * mu + EPS);
            const float mr = mu * rstd;
            float qv[H_];
            #pragma unroll
            for (int h = 0; h < H_; ++h) {
                qv[h] = elu1(rstd * dq[h] - mr * s_cst[h]     + s_cst[4 + h]  + bq[h]);
                const float kv = elu1(rstd * dk[h] - mr * s_cst[8 + h] + s_cst[12 + h] + bk[h]);
                aq[h] += qv[h]; ak[h] += kv; ak2[h] += kv * mr;
                s_kb[h][t] = (short)f2bf(kv * rstd);
            }
            uint2 qp;
            qp.x = ((unsigned)f2bf(qv[1]) << 16) | f2bf(qv[0]);
            qp.y = ((unsigned)f2bf(qv[3]) << 16) | f2bf(qv[2]);
            *reinterpret_cast<uint2*>(qb0 + (size_t)rr * 4) = qp;
        } else {
            #pragma unroll
            for (int e = 0; e < E_; ++e) s_xT[e][t] = 0;
            #pragma unroll
            for (int h = 0; h < H_; ++h) s_kb[h][t] = 0;
        }
        __syncthreads();
        #pragma unroll
        for (int ks = 0; ks < 8; ++ks) {
            bf16x8 af;
            #pragma unroll
            for (int i = 0; i < 8; ++i) af[i] = 0;
            if (lr < 4) af = *reinterpret_cast<const bf16x8*>(&s_kb[lr][ks * 32 + lq * 8]);
            const bf16x8 bf = *reinterpret_cast<const bf16x8*>(&s_xT[w * 16 + lr][ks * 32 + lq * 8]);
            uacc = __builtin_amdgcn_mfma_f32_16x16x32_bf16(af, bf, uacc, 0, 0, 0);
        }
        __syncthreads();
    }

    #pragma unroll
    for (int h = 0; h < H_; ++h) {
        #pragma unroll
        for (int off = 32; off; off >>= 1) {
            aq[h] += __shfl_xor(aq[h], off, 64);
            ak[h] += __shfl_xor(ak[h], off, 64);
            ak2[h] += __shfl_xor(ak2[h], off, 64);
        }
    }
    if (l == 0) {
        #pragma unroll
        for (int h = 0; h < H_; ++h) { red_q[w][h] = aq[h]; red_k[w][h] = ak[h]; red_k2[w][h] = ak2[h]; }
    }
    __syncthreads();
    if (t < H_) {
        float sq = 0.f, sk = 0.f, s1 = 0.f;
        #pragma unroll
        for (int w2 = 0; w2 < 4; ++w2) { sq += red_q[w2][t]; sk += red_k[w2][t]; s1 += red_k2[w2][t]; }
        s_qm[t] = sq * (1.f / R_);
        s_sk[t] = sk;
        s_S1[t] = s1;
    }
    __syncthreads();
    if (lq == 0) {
        const int e = w * 16 + lr;
        #pragma unroll
        for (int i = 0; i < 4; ++i)
            s_u[i][e] = lng[e] * (uacc[i] - s_S1[i]) + lnb[e] * s_sk[i];
    }
    __syncthreads();
    if (t < E_) {
        const int h = t >> 4;
        float acc = 0.f;
        #pragma unroll
        for (int e = 0; e < E_; ++e) acc += wv[t * E_ + e] * s_u[h][e];
        s_ktv[t] = acc / s_sk[h] + bv[t];
    }
    __syncthreads();
    if (t < E_) {
        #pragma unroll
        for (int h = 0; h < H_; ++h) {
            float acc = 0.f;
            #pragma unroll
            for (int d = 0; d < 16; ++d) acc += wo[t * E_ + h * 16 + d] * s_ktv[h * 16 + d];
            s_wok[t][h] = acc;
        }
    }
    __syncthreads();

    // wokq[(b*C + c)][e*4 + h] = wok[e][h]/qm[h]  (coalesced 1KB)
    {
        const int e = t >> 2, h = t & 3;
        wokq[((size_t)(b * C_ + c)) * 256 + t] = s_wok[e][h] / s_qm[h];
    }
}

// ---------------------------------------------------------------------------
// prep_weights: fp32 -> bf16 for w1/w2.
// ---------------------------------------------------------------------------
__global__ __launch_bounds__(256) void prep_weights(
    const float* __restrict__ w1, const float* __restrict__ w2,
    short* __restrict__ w1b, short* __restrict__ w2b)
{
    const int i = blockIdx.x * 256 + threadIdx.x;
    if (i < 16384) w1b[i] = (short)f2bf(w1[i]);
    else           w2b[i - 16384] = (short)f2bf(w2[i - 16384]);
}

// ---------------------------------------------------------------------------
// Kernel C: MFMA bf16 FFN with inline col-attn apply.
// hcol[e] = h[e] + col_bo[e] + sum_h q[h]*wokq[e][h]  (fp32, computed
// identically in phase 1 and store phase).
// ---------------------------------------------------------------------------
#define SA 72
#define SG 264
#define SO 65

__global__ __launch_bounds__(256) void ffn_mfma(
    const short* __restrict__ hbuf,
    const unsigned short* __restrict__ qbuf, const float* __restrict__ wokq,
    const float* __restrict__ cbo,
    const float* __restrict__ lng, const float* __restrict__ lnb,
    const short* __restrict__ w1b, const float* __restrict__ b1,
    const short* __restrict__ w2b, const float* __restrict__ b2,
    float* __restrict__ out)
{
    __shared__ __align__(16) char smem[33792 + 16640];
    short* s_g = (short*)smem;
    short* s_a = (short*)(smem + 33792);
    float* s_o = (float*)(smem + 33792);

    const int t = threadIdx.x;
    const int w = t >> 6;
    const int l = t & 63;
    const int lr = l & 15;
    const int lq = l >> 4;

    const int bid = blockIdx.x;
    const int cb  = bid & 7;
    const int rem = bid >> 3;
    const int r   = rem % R_;
    const int b   = rem / R_;
    const int c0  = cb * 64;

    const short* tile = hbuf + ((size_t)((size_t)b * R_ + r) * C_ + c0) * E_;

    // phase 1: coalesced tile read + inline col-attn + LN -> s_a[m][e]
    {
        const int m  = t >> 2;
        const int qi = t & 3;
        const int c  = c0 + m;
        const short* hp = tile + (size_t)t * 16;
        const bf16x8 v0 = *reinterpret_cast<const bf16x8*>(hp);
        const bf16x8 v1 = *reinterpret_cast<const bf16x8*>(hp + 8);
        const uint2 qp = *reinterpret_cast<const uint2*>(
            qbuf + ((size_t)(b * C_ + c) * R_ + r) * 4);
        float qv[4];
        qv[0] = bf2f((unsigned short)(qp.x & 0xFFFF));
        qv[1] = bf2f((unsigned short)(qp.x >> 16));
        qv[2] = bf2f((unsigned short)(qp.y & 0xFFFF));
        qv[3] = bf2f((unsigned short)(qp.y >> 16));
        const float* wqp = wokq + ((size_t)(b * C_ + c)) * 256 + qi * 64;
        float hc[16];
        #pragma unroll
        for (int i = 0; i < 16; ++i) {
            const int e = qi * 16 + i;
            const float hv = bf2f((unsigned short)(i < 8 ? v0[i] : v1[i - 8]));
            hc[i] = hv + cbo[e] + qv[0] * wqp[i * 4 + 0] + qv[1] * wqp[i * 4 + 1]
                               + qv[2] * wqp[i * 4 + 2] + qv[3] * wqp[i * 4 + 3];
        }
        float s = 0.f, ss = 0.f;
        #pragma unroll
        for (int i = 0; i < 16; ++i) { s += hc[i]; ss += hc[i] * hc[i]; }
        s  += __shfl_xor(s, 1, 64);  s  += __shfl_xor(s, 2, 64);
        ss += __shfl_xor(ss, 1, 64); ss += __shfl_xor(ss, 2, 64);
        const float mu = s * (1.f / 64.f);
        const float rstd = rsqrtf(ss * (1.f / 64.f) - mu * mu + EPS);
        bf16x8 o0, o1;
        #pragma unroll
        for (int i = 0; i < 8; ++i) {
            const int e = qi * 16 + i;
            o0[i] = (short)f2bf((hc[i] - mu) * rstd * lng[e] + lnb[e]);
        }
        #pragma unroll
        for (int i = 0; i < 8; ++i) {
            const int e = qi * 16 + 8 + i;
            o1[i] = (short)f2bf((hc[8 + i] - mu) * rstd * lng[e] + lnb[e]);
        }
        *reinterpret_cast<bf16x8*>(&s_a[m * SA + qi * 16])     = o0;
        *reinterpret_cast<bf16x8*>(&s_a[m * SA + qi * 16 + 8]) = o1;
    }
    __syncthreads();

    // GEMM1 (swapped): D1T = W1 x XN^T, GELU -> s_g
    {
        bf16x8 bfr[4][2];
        #pragma unroll
        for (int mt = 0; mt < 4; ++mt)
            #pragma unroll
            for (int ks = 0; ks < 2; ++ks)
                bfr[mt][ks] = *reinterpret_cast<const bf16x8*>(
                    &s_a[(mt * 16 + lr) * SA + ks * 32 + lq * 8]);

        #pragma unroll
        for (int nn = 0; nn < 4; ++nn) {
            const int jt = w * 4 + nn;
            bf16x8 afr[2];
            #pragma unroll
            for (int ks = 0; ks < 2; ++ks)
                afr[ks] = *reinterpret_cast<const bf16x8*>(
                    w1b + (size_t)(jt * 16 + lr) * 64 + ks * 32 + lq * 8);
            f32x4 acc[4];
            #pragma unroll
            for (int mt = 0; mt < 4; ++mt) { acc[mt][0]=0.f; acc[mt][1]=0.f; acc[mt][2]=0.f; acc[mt][3]=0.f; }
            #pragma unroll
            for (int ks = 0; ks < 2; ++ks)
                #pragma unroll
                for (int mt = 0; mt < 4; ++mt)
                    acc[mt] = __builtin_amdgcn_mfma_f32_16x16x32_bf16(afr[ks], bfr[mt][ks], acc[mt], 0, 0, 0);

            const float4 b1v = *reinterpret_cast<const float4*>(&b1[jt * 16 + lq * 4]);
            const float* b1p = (const float*)&b1v;
            #pragma unroll
            for (int mt = 0; mt < 4; ++mt) {
                const int m = mt * 16 + lr;
                bf16x4 pk;
                #pragma unroll
                for (int i = 0; i < 4; ++i) {
                    const float aa = acc[mt][i] + b1p[i];
                    pk[i] = (short)f2bf(gelu_fast(aa));
                }
                *reinterpret_cast<bf16x4*>(&s_g[m * SG + jt * 16 + lq * 4]) = pk;
            }
        }
    }
    __syncthreads();

    // GEMM2: D2 = G x w2^T
    {
        f32x4 acc2[4];
        #pragma unroll
        for (int mt = 0; mt < 4; ++mt) { acc2[mt][0]=0.f; acc2[mt][1]=0.f; acc2[mt][2]=0.f; acc2[mt][3]=0.f; }
        const int n = w * 16 + lr;
        #pragma unroll
        for (int ks = 0; ks < 8; ++ks) {
            const bf16x8 bfr = *reinterpret_cast<const bf16x8*>(
                w2b + (size_t)n * 256 + ks * 32 + lq * 8);
            #pragma unroll
            for (int mt = 0; mt < 4; ++mt) {
                const bf16x8 af = *reinterpret_cast<const bf16x8*>(
                    &s_g[(mt * 16 + lr) * SG + ks * 32 + lq * 8]);
                acc2[mt] = __builtin_amdgcn_mfma_f32_16x16x32_bf16(af, bfr, acc2[mt], 0, 0, 0);
            }
        }
        #pragma unroll
        for (int mt = 0; mt < 4; ++mt)
            #pragma unroll
            for (int i = 0; i < 4; ++i)
                s_o[(mt * 16 + lq * 4 + i) * SO + n] = acc2[mt][i];
    }
    __syncthreads();

    // store: recompute hcol (identical fp32 math) + b2 + ffn out, coalesced c
    {
        const int m  = t & 63;
        const int eb = (t >> 6) * 16;
        const int c  = c0 + m;
        const short* hp = tile + (size_t)m * E_ + eb;
        const bf16x8 v0 = *reinterpret_cast<const bf16x8*>(hp);
        const bf16x8 v1 = *reinterpret_cast<const bf16x8*>(hp + 8);
        const uint2 qp = *reinterpret_cast<const uint2*>(
            qbuf + ((size_t)(b * C_ + c) * R_ + r) * 4);
        float qv[4];
        qv[0] = bf2f((unsigned short)(qp.x & 0xFFFF));
        qv[1] = bf2f((unsigned short)(qp.x >> 16));
        qv[2] = bf2f((unsigned short)(qp.y & 0xFFFF));
        qv[3] = bf2f((unsigned short)(qp.y >> 16));
        const float* wqp = wokq + ((size_t)(b * C_ + c)) * 256 + eb * 4;
        const size_t RC = (size_t)R_ * C_;
        float* op = out + (size_t)b * E_ * RC + (size_t)r * C_ + c;
        #pragma unroll
        for (int i = 0; i < 16; ++i) {
            const int e = eb + i;
            const float hv = bf2f((unsigned short)(i < 8 ? v0[i] : v1[i - 8]));
            const float hc = hv + cbo[e] + qv[0] * wqp[i * 4 + 0] + qv[1] * wqp[i * 4 + 1]
                                         + qv[2] * wqp[i * 4 + 2] + qv[3] * wqp[i * 4 + 3];
            op[(size_t)e * RC] = hc + b2[e] + s_o[m * SO + e];
        }
    }
}

extern "C" void kernel_launch(void* const* d_in, const int* in_sizes, int n_in,
                              void* d_out, int out_size, void* d_ws, size_t ws_size,
                              hipStream_t stream) {
    const float* x      = (const float*)d_in[0];
    const float* row_wq = (const float*)d_in[1];
    const float* row_bq = (const float*)d_in[2];
    const float* row_wk = (const float*)d_in[3];
    const float* row_bk = (const float*)d_in[4];
    const float* row_wv = (const float*)d_in[5];
    const float* row_bv = (const float*)d_in[6];
    const float* row_wo = (const float*)d_in[7];
    const float* row_bo = (const float*)d_in[8];
    const float* col_wq = (const float*)d_in[9];
    const float* col_bq = (const float*)d_in[10];
    const float* col_wk = (const float*)d_in[11];
    const float* col_bk = (const float*)d_in[12];
    const float* col_wv = (const float*)d_in[13];
    const float* col_bv = (const float*)d_in[14];
    const float* col_wo = (const float*)d_in[15];
    const float* col_bo = (const float*)d_in[16];
    const float* rn_g   = (const float*)d_in[17];
    const float* rn_b   = (const float*)d_in[18];
    const float* cn_g   = (const float*)d_in[19];
    const float* cn_b   = (const float*)d_in[20];
    const float* fn_g   = (const float*)d_in[21];
    const float* fn_b   = (const float*)d_in[22];
    const float* w1     = (const float*)d_in[23];
    const float* b1     = (const float*)d_in[24];
    const float* w2     = (const float*)d_in[25];
    const float* b2     = (const float*)d_in[26];

    const size_t n_h   = (size_t)B_ * R_ * C_ * E_;          // bf16 elements
    const size_t n_q   = (size_t)B_ * C_ * R_ * 4;           // bf16 elements
    const size_t n_wok = (size_t)B_ * C_ * 256;              // f32 elements
    const size_t need  = n_h * 2 + n_q * 2 + n_wok * 4 + 2 * 16384 * 2;
    if (ws_size < need) return;

    short* hbuf = (short*)d_ws;
    unsigned short* qbuf = (unsigned short*)(hbuf + n_h);
    float* wokq = (float*)(qbuf + n_q);
    short* w1b = (short*)(wokq + n_wok);
    short* w2b = w1b + 16384;

    row_attn<<<dim3(R_, B_), 512, 0, stream>>>(
        x, row_wq, row_bq, row_wk, row_bk, row_wv, row_bv, row_wo, row_bo,
        rn_g, rn_b, hbuf);
    prep_weights<<<128, 256, 0, stream>>>(w1, w2, w1b, w2b);
    col_stats<<<dim3(C_, B_), 256, 0, stream>>>(
        hbuf, col_wq, col_bq, col_wk, col_bk, col_wv, col_bv, col_wo,
        cn_g, cn_b, qbuf, wokq);
    ffn_mfma<<<B_ * R_ * 8, 256, 0, stream>>>(
        hbuf, qbuf, wokq, col_bo, fn_g, fn_b, w1b, b1, w2b, b2, (float*)d_out);
}

// Round 13
// 724.081 us; speedup vs baseline: 2.0442x; 1.2104x over previous
//
#include <hip/hip_runtime.h>
#include <cmath>

#define E_ 64
#define H_ 4
#define B_ 2
#define R_ 1225
#define C_ 512
#define EPS 1e-5f

__device__ __forceinline__ float elu1(float a) { return a > 0.f ? a + 1.f : __expf(a); }

typedef float f32x4 __attribute__((ext_vector_type(4)));
typedef short bf16x8 __attribute__((ext_vector_type(8)));
typedef short bf16x4 __attribute__((ext_vector_type(4)));

__device__ __forceinline__ unsigned short f2bf(float f) {
    union { float f; unsigned u; } c; c.f = f;
    unsigned u = c.u + 0x7FFFu + ((c.u >> 16) & 1u);   // RNE
    return (unsigned short)(u >> 16);
}

__device__ __forceinline__ float bf2f(unsigned short s) {
    union { unsigned u; float f; } c; c.u = ((unsigned)s) << 16;
    return c.f;
}

// tanh-approx GELU in sigmoid form (max dev ~3e-4 vs exact-erf)
__device__ __forceinline__ float gelu_fast(float a) {
    const float u = a * (-1.5957691216057308f - 0.0713548162726009f * a * a);
    return a / (1.f + __expf(u));
}

// ---------------------------------------------------------------------------
// Pipeline (round 13):
//  row_attn  : x -> h (bf16, (B,R,C,E))                      [unchanged r11]
//  col_stats : h -> qbuf (B,C,R,4) bf16 + wokq (B,C,E,4) f32 [unchanged r12]
//  ffn_mfma  : col-apply computed ONCE, hcol kept in REGISTERS through to
//              the store (phase-1 mapping == store mapping; LN partial-sum
//              via 2KB LDS). No store-phase recompute / re-loads.
// ---------------------------------------------------------------------------

#define SXR 520   // 512+8 pad

__global__ __launch_bounds__(512, 2) void row_attn(
    const float* __restrict__ x,
    const float* __restrict__ wq, const float* __restrict__ bq,
    const float* __restrict__ wk, const float* __restrict__ bk,
    const float* __restrict__ wv, const float* __restrict__ bv,
    const float* __restrict__ wo, const float* __restrict__ bo,
    const float* __restrict__ lng, const float* __restrict__ lnb,
    short* __restrict__ hout)
{
    const int r = blockIdx.x;
    const int b = blockIdx.y;
    const int t = threadIdx.x;      // 0..511 == c
    const int w = t >> 6;
    const int l = t & 63;
    const int lr = l & 15;
    const int lq = l >> 4;

    __shared__ short s_xT[E_][SXR];
    __shared__ short s_kb[4][SXR];
    __shared__ float s_upart[2][H_][E_];
    __shared__ float s_ktv[E_];
    __shared__ float s_wok[E_][H_];
    __shared__ float s_qm[H_];
    __shared__ float s_sk[H_];
    __shared__ float s_S1[H_];
    __shared__ float red_q[8][H_];
    __shared__ float red_k[8][H_];
    __shared__ float red_k2[8][H_];
    __shared__ float s_cst[16];

    if (t < 16) {
        const int h = t & 3;
        const int kind = t >> 2;
        const float* wm = (kind < 2) ? wq : wk;
        const float* vm = (kind & 1) ? lnb : lng;
        float acc = 0.f;
        for (int e = 0; e < E_; ++e) acc += wm[h * E_ + e] * vm[e];
        s_cst[t] = acc;
    }
    __syncthreads();

    const size_t RC = (size_t)R_ * C_;
    const float* xbase = x + (size_t)b * E_ * RC + (size_t)r * C_;

    float qs[H_];
    float aq[H_], ak[H_], ak2[H_];
    {
        const float* xp = xbase + t;
        float s = 0.f, ss = 0.f;
        float dq[H_] = {0.f, 0.f, 0.f, 0.f};
        float dk[H_] = {0.f, 0.f, 0.f, 0.f};
        #pragma unroll 16
        for (int e = 0; e < E_; ++e) {
            const float xv = xp[(size_t)e * RC];
            s += xv; ss += xv * xv;
            const float t1 = lng[e] * xv;
            #pragma unroll
            for (int h = 0; h < H_; ++h) { dq[h] += wq[h * E_ + e] * t1; dk[h] += wk[h * E_ + e] * t1; }
            s_xT[e][t] = (short)f2bf(xv);
        }
        const float mu = s * (1.f / E_);
        const float rstd = rsqrtf(ss * (1.f / E_) - mu * mu + EPS);
        const float mr = mu * rstd;
        #pragma unroll
        for (int h = 0; h < H_; ++h) {
            const float qv = elu1(rstd * dq[h] - mr * s_cst[h]     + s_cst[4 + h]  + bq[h]);
            const float kv = elu1(rstd * dk[h] - mr * s_cst[8 + h] + s_cst[12 + h] + bk[h]);
            qs[h] = qv;
            aq[h] = qv; ak[h] = kv; ak2[h] = kv * mr;
            s_kb[h][t] = (short)f2bf(kv * rstd);
        }
    }
    __syncthreads();

    {
        const int et = w & 3;
        const int kh = w >> 2;
        f32x4 uacc; uacc[0] = uacc[1] = uacc[2] = uacc[3] = 0.f;
        #pragma unroll
        for (int ks = 0; ks < 8; ++ks) {
            const int co = kh * 256 + ks * 32 + lq * 8;
            bf16x8 af;
            #pragma unroll
            for (int i = 0; i < 8; ++i) af[i] = 0;
            if (lr < 4) af = *reinterpret_cast<const bf16x8*>(&s_kb[lr][co]);
            const bf16x8 bf = *reinterpret_cast<const bf16x8*>(&s_xT[et * 16 + lr][co]);
            uacc = __builtin_amdgcn_mfma_f32_16x16x32_bf16(af, bf, uacc, 0, 0, 0);
        }
        if (lq == 0) {
            #pragma unroll
            for (int i = 0; i < 4; ++i) s_upart[kh][i][et * 16 + lr] = uacc[i];
        }
    }

    #pragma unroll
    for (int h = 0; h < H_; ++h) {
        #pragma unroll
        for (int off = 32; off; off >>= 1) {
            aq[h] += __shfl_xor(aq[h], off, 64);
            ak[h] += __shfl_xor(ak[h], off, 64);
            ak2[h] += __shfl_xor(ak2[h], off, 64);
        }
    }
    if (l == 0) {
        #pragma unroll
        for (int h = 0; h < H_; ++h) { red_q[w][h] = aq[h]; red_k[w][h] = ak[h]; red_k2[w][h] = ak2[h]; }
    }
    __syncthreads();
    if (t < H_) {
        float sq = 0.f, sk = 0.f, s1 = 0.f;
        #pragma unroll
        for (int w2 = 0; w2 < 8; ++w2) { sq += red_q[w2][t]; sk += red_k[w2][t]; s1 += red_k2[w2][t]; }
        s_qm[t] = sq * (1.f / C_);
        s_sk[t] = sk;
        s_S1[t] = s1;
    }
    __syncthreads();
    if (t < H_ * E_) {
        const int h = t >> 6, e = t & 63;
        const float m1 = s_upart[0][h][e] + s_upart[1][h][e];
        s_upart[0][h][e] = lng[e] * (m1 - s_S1[h]) + lnb[e] * s_sk[h];
    }
    __syncthreads();
    if (t < E_) {
        const int h = t >> 4;
        float acc = 0.f;
        #pragma unroll
        for (int e = 0; e < E_; ++e) acc += wv[t * E_ + e] * s_upart[0][h][e];
        s_ktv[t] = acc / s_sk[h] + bv[t];
    }
    __syncthreads();
    if (t < E_) {
        #pragma unroll
        for (int h = 0; h < H_; ++h) {
            float acc = 0.f;
            #pragma unroll
            for (int d = 0; d < 16; ++d) acc += wo[t * E_ + h * 16 + d] * s_ktv[h * 16 + d];
            s_wok[t][h] = acc;
        }
    }
    __syncthreads();

    {
        float qn[H_];
        #pragma unroll
        for (int h = 0; h < H_; ++h) qn[h] = qs[h] / s_qm[h];
        short* hp = hout + ((size_t)((size_t)b * R_ + r) * C_ + t) * E_;
        #pragma unroll
        for (int e8 = 0; e8 < 8; ++e8) {
            bf16x8 o;
            #pragma unroll
            for (int i = 0; i < 8; ++i) {
                const int e = e8 * 8 + i;
                float tt = bo[e];
                #pragma unroll
                for (int h = 0; h < H_; ++h) tt += qn[h] * s_wok[e][h];
                o[i] = (short)f2bf(bf2f((unsigned short)s_xT[e][t]) + tt);
            }
            *reinterpret_cast<bf16x8*>(hp + e8 * 8) = o;
        }
    }
}

// ---------------------------------------------------------------------------
// col_stats (unchanged r12): stats only, no h rewrite.
// ---------------------------------------------------------------------------
#define SX 264

__global__ __launch_bounds__(256, 3) void col_stats(
    const short* __restrict__ hbuf,
    const float* __restrict__ wq, const float* __restrict__ bq,
    const float* __restrict__ wk, const float* __restrict__ bk,
    const float* __restrict__ wv, const float* __restrict__ bv,
    const float* __restrict__ wo,
    const float* __restrict__ lng, const float* __restrict__ lnb,
    unsigned short* __restrict__ qbuf, float* __restrict__ wokq)
{
    const int c = blockIdx.x;
    const int b = blockIdx.y;
    const int t = threadIdx.x;
    const int w = t >> 6;
    const int l = t & 63;
    const int lr = l & 15;
    const int lq = l >> 4;

    __shared__ short s_xT[E_][SX];
    __shared__ short s_kb[4][SX];
    __shared__ float s_u[H_][E_];
    __shared__ float s_ktv[E_];
    __shared__ float s_wok[E_][H_];
    __shared__ float s_qm[H_];
    __shared__ float s_sk[H_];
    __shared__ float s_S1[H_];
    __shared__ float red_q[4][H_];
    __shared__ float red_k[4][H_];
    __shared__ float red_k2[4][H_];
    __shared__ float s_cst[16];

    if (t < 16) {
        const int h = t & 3;
        const int kind = t >> 2;
        const float* wm = (kind < 2) ? wq : wk;
        const float* vm = (kind & 1) ? lnb : lng;
        float acc = 0.f;
        for (int e = 0; e < E_; ++e) acc += wm[h * E_ + e] * vm[e];
        s_cst[t] = acc;
    }
    __syncthreads();

    const size_t CE = (size_t)C_ * E_;
    const short* hp0 = hbuf + (size_t)b * R_ * CE + (size_t)c * E_;
    unsigned short* qb0 = qbuf + ((size_t)(b * C_ + c)) * R_ * 4;

    float aq[H_]  = {0.f, 0.f, 0.f, 0.f};
    float ak[H_]  = {0.f, 0.f, 0.f, 0.f};
    float ak2[H_] = {0.f, 0.f, 0.f, 0.f};
    f32x4 uacc; uacc[0] = uacc[1] = uacc[2] = uacc[3] = 0.f;

    #pragma unroll 1
    for (int it = 0; it < 5; ++it) {
        const int rr = it * 256 + t;
        if (rr < R_) {
            const short* pp = hp0 + (size_t)rr * CE;
            bf16x8 hv8[8];
            #pragma unroll
            for (int g = 0; g < 8; ++g) hv8[g] = *reinterpret_cast<const bf16x8*>(pp + g * 8);
            float s = 0.f, ss = 0.f;
            float dq[H_] = {0.f, 0.f, 0.f, 0.f};
            float dk[H_] = {0.f, 0.f, 0.f, 0.f};
            #pragma unroll
            for (int g = 0; g < 8; ++g) {
                #pragma unroll
                for (int i = 0; i < 8; ++i) {
                    const int e = g * 8 + i;
                    const float xv = bf2f((unsigned short)hv8[g][i]);
                    s += xv; ss += xv * xv;
                    const float t1 = lng[e] * xv;
                    #pragma unroll
                    for (int h = 0; h < H_; ++h) { dq[h] += wq[h * E_ + e] * t1; dk[h] += wk[h * E_ + e] * t1; }
                    s_xT[e][t] = hv8[g][i];
                }
            }
            const float mu = s * (1.f / E_);
            const float rstd = rsqrtf(ss * (1.f / E_) - mu * mu + EPS);
            const float mr = mu * rstd;
            float qv[H_];
            #pragma unroll
            for (int h = 0; h < H_; ++h) {
                qv[h] = elu1(rstd * dq[h] - mr * s_cst[h]     + s_cst[4 + h]  + bq[h]);
                const float kv = elu1(rstd * dk[h] - mr * s_cst[8 + h] + s_cst[12 + h] + bk[h]);
                aq[h] += qv[h]; ak[h] += kv; ak2[h] += kv * mr;
                s_kb[h][t] = (short)f2bf(kv * rstd);
            }
            uint2 qp;
            qp.x = ((unsigned)f2bf(qv[1]) << 16) | f2bf(qv[0]);
            qp.y = ((unsigned)f2bf(qv[3]) << 16) | f2bf(qv[2]);
            *reinterpret_cast<uint2*>(qb0 + (size_t)rr * 4) = qp;
        } else {
            #pragma unroll
            for (int e = 0; e < E_; ++e) s_xT[e][t] = 0;
            #pragma unroll
            for (int h = 0; h < H_; ++h) s_kb[h][t] = 0;
        }
        __syncthreads();
        #pragma unroll
        for (int ks = 0; ks < 8; ++ks) {
            bf16x8 af;
            #pragma unroll
            for (int i = 0; i < 8; ++i) af[i] = 0;
            if (lr < 4) af = *reinterpret_cast<const bf16x8*>(&s_kb[lr][ks * 32 + lq * 8]);
            const bf16x8 bf = *reinterpret_cast<const bf16x8*>(&s_xT[w * 16 + lr][ks * 32 + lq * 8]);
            uacc = __builtin_amdgcn_mfma_f32_16x16x32_bf16(af, bf, uacc, 0, 0, 0);
        }
        __syncthreads();
    }

    #pragma unroll
    for (int h = 0; h < H_; ++h) {
        #pragma unroll
        for (int off = 32; off; off >>= 1) {
            aq[h] += __shfl_xor(aq[h], off, 64);
            ak[h] += __shfl_xor(ak[h], off, 64);
            ak2[h] += __shfl_xor(ak2[h], off, 64);
        }
    }
    if (l == 0) {
        #pragma unroll
        for (int h = 0; h < H_; ++h) { red_q[w][h] = aq[h]; red_k[w][h] = ak[h]; red_k2[w][h] = ak2[h]; }
    }
    __syncthreads();
    if (t < H_) {
        float sq = 0.f, sk = 0.f, s1 = 0.f;
        #pragma unroll
        for (int w2 = 0; w2 < 4; ++w2) { sq += red_q[w2][t]; sk += red_k[w2][t]; s1 += red_k2[w2][t]; }
        s_qm[t] = sq * (1.f / R_);
        s_sk[t] = sk;
        s_S1[t] = s1;
    }
    __syncthreads();
    if (lq == 0) {
        const int e = w * 16 + lr;
        #pragma unroll
        for (int i = 0; i < 4; ++i)
            s_u[i][e] = lng[e] * (uacc[i] - s_S1[i]) + lnb[e] * s_sk[i];
    }
    __syncthreads();
    if (t < E_) {
        const int h = t >> 4;
        float acc = 0.f;
        #pragma unroll
        for (int e = 0; e < E_; ++e) acc += wv[t * E_ + e] * s_u[h][e];
        s_ktv[t] = acc / s_sk[h] + bv[t];
    }
    __syncthreads();
    if (t < E_) {
        #pragma unroll
        for (int h = 0; h < H_; ++h) {
            float acc = 0.f;
            #pragma unroll
            for (int d = 0; d < 16; ++d) acc += wo[t * E_ + h * 16 + d] * s_ktv[h * 16 + d];
            s_wok[t][h] = acc;
        }
    }
    __syncthreads();

    {
        const int e = t >> 2, h = t & 3;
        wokq[((size_t)(b * C_ + c)) * 256 + t] = s_wok[e][h] / s_qm[h];
    }
}

// ---------------------------------------------------------------------------
// prep_weights (unchanged).
// ---------------------------------------------------------------------------
__global__ __launch_bounds__(256) void prep_weights(
    const float* __restrict__ w1, const float* __restrict__ w2,
    short* __restrict__ w1b, short* __restrict__ w2b)
{
    const int i = blockIdx.x * 256 + threadIdx.x;
    if (i < 16384) w1b[i] = (short)f2bf(w1[i]);
    else           w2b[i - 16384] = (short)f2bf(w2[i - 16384]);
}

// ---------------------------------------------------------------------------
// ffn_mfma v3: hcol in registers end-to-end.
// Thread mapping (BOTH phase 1 and store): m = lane (position), eb = wave*16.
// LN partial sums via 2KB LDS (dead tail of s_o region) + 1 barrier.
// ---------------------------------------------------------------------------
#define SA 72
#define SG 264
#define SO 65

__global__ __launch_bounds__(256) void ffn_mfma(
    const short* __restrict__ hbuf,
    const unsigned short* __restrict__ qbuf, const float* __restrict__ wokq,
    const float* __restrict__ cbo,
    const float* __restrict__ lng, const float* __restrict__ lnb,
    const short* __restrict__ w1b, const float* __restrict__ b1,
    const short* __restrict__ w2b, const float* __restrict__ b2,
    float* __restrict__ out)
{
    __shared__ __align__(16) char smem[33792 + 16640];
    short* s_g = (short*)smem;
    short* s_a = (short*)(smem + 33792);
    float* s_o = (float*)(smem + 33792);
    // LN partials: [0..255]=s by (w*64+m), [256..511]=ss. Lives in s_o's tail
    // region [43008, 45056) — written/read in phase 1, dead before s_o writes.
    float* s_ln = (float*)(smem + 43008);

    const int t = threadIdx.x;
    const int w = t >> 6;
    const int l = t & 63;
    const int lr = l & 15;
    const int lq = l >> 4;

    const int bid = blockIdx.x;
    const int cb  = bid & 7;
    const int rem = bid >> 3;
    const int r   = rem % R_;
    const int b   = rem / R_;
    const int c0  = cb * 64;

    const short* tile = hbuf + ((size_t)((size_t)b * R_ + r) * C_ + c0) * E_;

    // ---- phase 1a: tile read + col-apply -> hc[16] (REGISTERS) ----------
    const int m  = l;            // position within tile (c = c0 + m)
    const int eb = w * 16;       // e-range [eb, eb+16)
    float hc[16];
    {
        const short* hp = tile + (size_t)m * E_ + eb;
        const bf16x8 v0 = *reinterpret_cast<const bf16x8*>(hp);
        const bf16x8 v1 = *reinterpret_cast<const bf16x8*>(hp + 8);
        const uint2 qp = *reinterpret_cast<const uint2*>(
            qbuf + ((size_t)(b * C_ + c0 + m) * R_ + r) * 4);
        float qv[4];
        qv[0] = bf2f((unsigned short)(qp.x & 0xFFFF));
        qv[1] = bf2f((unsigned short)(qp.x >> 16));
        qv[2] = bf2f((unsigned short)(qp.y & 0xFFFF));
        qv[3] = bf2f((unsigned short)(qp.y >> 16));
        const float4* wq4 = reinterpret_cast<const float4*>(
            wokq + ((size_t)(b * C_ + c0 + m)) * 256) + eb;
        float s = 0.f, ss = 0.f;
        #pragma unroll
        for (int i = 0; i < 16; ++i) {
            const int e = eb + i;
            const float4 f4 = wq4[i];
            const float hv = bf2f((unsigned short)(i < 8 ? v0[i] : v1[i - 8]));
            hc[i] = hv + cbo[e] + qv[0] * f4.x + qv[1] * f4.y + qv[2] * f4.z + qv[3] * f4.w;
            s += hc[i]; ss += hc[i] * hc[i];
        }
        s_ln[w * 64 + m]       = s;
        s_ln[256 + w * 64 + m] = ss;
    }
    __syncthreads();

    // ---- phase 1b: full-position LN -> xn bf16 -> s_a[m][eb..eb+16) -----
    {
        const float s  = s_ln[m] + s_ln[64 + m] + s_ln[128 + m] + s_ln[192 + m];
        const float ss = s_ln[256 + m] + s_ln[320 + m] + s_ln[384 + m] + s_ln[448 + m];
        const float mu = s * (1.f / 64.f);
        const float rstd = rsqrtf(ss * (1.f / 64.f) - mu * mu + EPS);
        bf16x8 o0, o1;
        #pragma unroll
        for (int i = 0; i < 8; ++i) {
            const int e = eb + i;
            o0[i] = (short)f2bf((hc[i] - mu) * rstd * lng[e] + lnb[e]);
        }
        #pragma unroll
        for (int i = 0; i < 8; ++i) {
            const int e = eb + 8 + i;
            o1[i] = (short)f2bf((hc[8 + i] - mu) * rstd * lng[e] + lnb[e]);
        }
        *reinterpret_cast<bf16x8*>(&s_a[m * SA + eb])     = o0;
        *reinterpret_cast<bf16x8*>(&s_a[m * SA + eb + 8]) = o1;
    }
    __syncthreads();

    // ---- GEMM1 (swapped): D1T = W1 x XN^T, GELU -> s_g -------------------
    {
        bf16x8 bfr[4][2];
        #pragma unroll
        for (int mt = 0; mt < 4; ++mt)
            #pragma unroll
            for (int ks = 0; ks < 2; ++ks)
                bfr[mt][ks] = *reinterpret_cast<const bf16x8*>(
                    &s_a[(mt * 16 + lr) * SA + ks * 32 + lq * 8]);

        #pragma unroll
        for (int nn = 0; nn < 4; ++nn) {
            const int jt = w * 4 + nn;
            bf16x8 afr[2];
            #pragma unroll
            for (int ks = 0; ks < 2; ++ks)
                afr[ks] = *reinterpret_cast<const bf16x8*>(
                    w1b + (size_t)(jt * 16 + lr) * 64 + ks * 32 + lq * 8);
            f32x4 acc[4];
            #pragma unroll
            for (int mt = 0; mt < 4; ++mt) { acc[mt][0]=0.f; acc[mt][1]=0.f; acc[mt][2]=0.f; acc[mt][3]=0.f; }
            #pragma unroll
            for (int ks = 0; ks < 2; ++ks)
                #pragma unroll
                for (int mt = 0; mt < 4; ++mt)
                    acc[mt] = __builtin_amdgcn_mfma_f32_16x16x32_bf16(afr[ks], bfr[mt][ks], acc[mt], 0, 0, 0);

            const float4 b1v = *reinterpret_cast<const float4*>(&b1[jt * 16 + lq * 4]);
            const float* b1p = (const float*)&b1v;
            #pragma unroll
            for (int mt = 0; mt < 4; ++mt) {
                const int mm = mt * 16 + lr;
                bf16x4 pk;
                #pragma unroll
                for (int i = 0; i < 4; ++i) {
                    const float aa = acc[mt][i] + b1p[i];
                    pk[i] = (short)f2bf(gelu_fast(aa));
                }
                *reinterpret_cast<bf16x4*>(&s_g[mm * SG + jt * 16 + lq * 4]) = pk;
            }
        }
    }
    __syncthreads();

    // ---- GEMM2: D2 = G x w2^T -> s_o ------------------------------------
    {
        f32x4 acc2[4];
        #pragma unroll
        for (int mt = 0; mt < 4; ++mt) { acc2[mt][0]=0.f; acc2[mt][1]=0.f; acc2[mt][2]=0.f; acc2[mt][3]=0.f; }
        const int n = w * 16 + lr;
        #pragma unroll
        for (int ks = 0; ks < 8; ++ks) {
            const bf16x8 bfr = *reinterpret_cast<const bf16x8*>(
                w2b + (size_t)n * 256 + ks * 32 + lq * 8);
            #pragma unroll
            for (int mt = 0; mt < 4; ++mt) {
                const bf16x8 af = *reinterpret_cast<const bf16x8*>(
                    &s_g[(mt * 16 + lr) * SG + ks * 32 + lq * 8]);
                acc2[mt] = __builtin_amdgcn_mfma_f32_16x16x32_bf16(af, bfr, acc2[mt], 0, 0, 0);
            }
        }
        #pragma unroll
        for (int mt = 0; mt < 4; ++mt)
            #pragma unroll
            for (int i = 0; i < 4; ++i)
                s_o[(mt * 16 + lq * 4 + i) * SO + n] = acc2[mt][i];
    }
    __syncthreads();

    // ---- store: out = hc (regs) + b2 + s_o, coalesced along c ------------
    {
        const size_t RC = (size_t)R_ * C_;
        float* op = out + (size_t)b * E_ * RC + (size_t)r * C_ + (c0 + m);
        #pragma unroll
        for (int i = 0; i < 16; ++i) {
            const int e = eb + i;
            op[(size_t)e * RC] = hc[i] + b2[e] + s_o[m * SO + e];
        }
    }
}

extern "C" void kernel_launch(void* const* d_in, const int* in_sizes, int n_in,
                              void* d_out, int out_size, void* d_ws, size_t ws_size,
                              hipStream_t stream) {
    const float* x      = (const float*)d_in[0];
    const float* row_wq = (const float*)d_in[1];
    const float* row_bq = (const float*)d_in[2];
    const float* row_wk = (const float*)d_in[3];
    const float* row_bk = (const float*)d_in[4];
    const float* row_wv = (const float*)d_in[5];
    const float* row_bv = (const float*)d_in[6];
    const float* row_wo = (const float*)d_in[7];
    const float* row_bo = (const float*)d_in[8];
    const float* col_wq = (const float*)d_in[9];
    const float* col_bq = (const float*)d_in[10];
    const float* col_wk = (const float*)d_in[11];
    const float* col_bk = (const float*)d_in[12];
    const float* col_wv = (const float*)d_in[13];
    const float* col_bv = (const float*)d_in[14];
    const float* col_wo = (const float*)d_in[15];
    const float* col_bo = (const float*)d_in[16];
    const float* rn_g   = (const float*)d_in[17];
    const float* rn_b   = (const float*)d_in[18];
    const float* cn_g   = (const float*)d_in[19];
    const float* cn_b   = (const float*)d_in[20];
    const float* fn_g   = (const float*)d_in[21];
    const float* fn_b   = (const float*)d_in[22];
    const float* w1     = (const float*)d_in[23];
    const float* b1     = (const float*)d_in[24];
    const float* w2     = (const float*)d_in[25];
    const float* b2     = (const float*)d_in[26];

    const size_t n_h   = (size_t)B_ * R_ * C_ * E_;          // bf16 elements
    const size_t n_q   = (size_t)B_ * C_ * R_ * 4;           // bf16 elements
    const size_t n_wok = (size_t)B_ * C_ * 256;              // f32 elements
    const size_t need  = n_h * 2 + n_q * 2 + n_wok * 4 + 2 * 16384 * 2;
    if (ws_size < need) return;

    short* hbuf = (short*)d_ws;
    unsigned short* qbuf = (unsigned short*)(hbuf + n_h);
    float* wokq = (float*)(qbuf + n_q);
    short* w1b = (short*)(wokq + n_wok);
    short* w2b = w1b + 16384;

    row_attn<<<dim3(R_, B_), 512, 0, stream>>>(
        x, row_wq, row_bq, row_wk, row_bk, row_wv, row_bv, row_wo, row_bo,
        rn_g, rn_b, hbuf);
    prep_weights<<<128, 256, 0, stream>>>(w1, w2, w1b, w2b);
    col_stats<<<dim3(C_, B_), 256, 0, stream>>>(
        hbuf, col_wq, col_bq, col_wk, col_bk, col_wv, col_bv, col_wo,
        cn_g, cn_b, qbuf, wokq);
    ffn_mfma<<<B_ * R_ * 8, 256, 0, stream>>>(
        hbuf, qbuf, wokq, col_bo, fn_g, fn_b, w1b, b1, w2b, b2, (float*)d_out);
}